// Round 1
// baseline (28855.478 us; speedup 1.0000x reference)
//
#include <hip/hip_runtime.h>
#include <hip/hip_bf16.h>
#include <math.h>

// Problem constants
// B=256, T=128; text 768->256, audio 74->128, video 35->128
// z = [audio(128) | video(128) | text(256)] per (b,t); LEN=512
// combined gate rows: [text 0..1023 | audio 1024..1535 | video 1536..2047]

__device__ __forceinline__ float sigm(float x) { return 1.0f / (1.0f + __expf(-x)); }
__device__ __forceinline__ float tanh_(float x) {
    float ax = fabsf(x);
    float e  = __expf(-2.0f * ax);
    float t  = (1.0f - e) / (1.0f + e);
    return copysignf(t, x);
}

// ---------------------------------------------------------------------------
// Generic C[M,N] = A[M,K] * W[N,K]^T + bias[N].  M,N multiples of 128.
// 128x128 tile, BK=16, 256 threads, 8x8 micro-tile. K-tail guarded (74/35).
// ---------------------------------------------------------------------------
__global__ __launch_bounds__(256) void gemm_bias(
    const float* __restrict__ A, const float* __restrict__ W,
    const float* __restrict__ bias, float* __restrict__ C,
    int M, int N, int K)
{
    constexpr int BM = 128, BN = 128, BK = 16;
    __shared__ float As[BK][BM + 4];
    __shared__ float Ws[BK][BN + 4];

    const int tid = threadIdx.x;
    const int bm  = blockIdx.y * BM;
    const int bn  = blockIdx.x * BN;

    const int lr = tid >> 1;          // 0..127
    const int lc = (tid & 1) * 8;     // 0 or 8
    const int tm = (tid >> 4) * 8;    // 0..120
    const int tn = (tid & 15) * 8;    // 0..120

    float acc[8][8];
#pragma unroll
    for (int i = 0; i < 8; ++i)
#pragma unroll
        for (int j = 0; j < 8; ++j) acc[i][j] = 0.f;

    for (int k0 = 0; k0 < K; k0 += BK) {
#pragma unroll
        for (int j = 0; j < 8; ++j) {
            int kk = lc + j, kg = k0 + kk;
            float va = 0.f, vw = 0.f;
            if (kg < K) {
                va = A[(size_t)(bm + lr) * K + kg];
                vw = W[(size_t)(bn + lr) * K + kg];
            }
            As[kk][lr] = va;
            Ws[kk][lr] = vw;
        }
        __syncthreads();
#pragma unroll
        for (int kk = 0; kk < BK; ++kk) {
            float a[8], w[8];
            *(float4*)&a[0] = *(const float4*)&As[kk][tm];
            *(float4*)&a[4] = *(const float4*)&As[kk][tm + 4];
            *(float4*)&w[0] = *(const float4*)&Ws[kk][tn];
            *(float4*)&w[4] = *(const float4*)&Ws[kk][tn + 4];
#pragma unroll
            for (int i = 0; i < 8; ++i)
#pragma unroll
                for (int j = 0; j < 8; ++j)
                    acc[i][j] = fmaf(a[i], w[j], acc[i][j]);
        }
        __syncthreads();
    }

#pragma unroll
    for (int i = 0; i < 8; ++i) {
#pragma unroll
        for (int j = 0; j < 8; ++j) {
            C[(size_t)(bm + tm + i) * N + (bn + tn + j)] = acc[i][j] + bias[bn + tn + j];
        }
    }
}

// ---------------------------------------------------------------------------
// Pack W_hh (all 3 modalities) transposed: WT[k][col], col in [0,2048)
//   col <1024: text row=col (K=256); 1024..1535: audio (K=128); else video.
// Zero-fill unused k>=128 region for audio/video (never read, but safe).
// ---------------------------------------------------------------------------
__global__ void wt_pack(const float* __restrict__ Wt, const float* __restrict__ Wa,
                        const float* __restrict__ Wv, float* __restrict__ WT)
{
    int idx = blockIdx.x * 256 + threadIdx.x;   // 256*2048 total
    int k   = idx >> 11;
    int col = idx & 2047;
    float v;
    if (col < 1024)      v = Wt[(size_t)col * 256 + k];
    else if (col < 1536) v = (k < 128) ? Wa[(size_t)(col - 1024) * 128 + k] : 0.f;
    else                 v = (k < 128) ? Wv[(size_t)(col - 1536) * 128 + k] : 0.f;
    WT[idx] = v;
}

// ---------------------------------------------------------------------------
// LSTM recurrence, all 3 modalities fused. 64 blocks x 128 threads.
// Block owns 4 batch rows for all 128 steps (batches independent -> no
// inter-block sync). h broadcast via LDS [coord][batch4]; gates staged in
// LDS; c lives in registers. Writes z[b][t][512] = [audio|video|text] h.
// ---------------------------------------------------------------------------
__global__ __launch_bounds__(128) void lstm_rec(
    const float* __restrict__ xpt, const float* __restrict__ xpa,
    const float* __restrict__ xpv, const float* __restrict__ WT,
    float* __restrict__ z)
{
    __shared__ float h_s[512][4];     // [coord][batch]  8 KB
    __shared__ float g_s[4][2048];    // [batch][combined gate row] 32 KB

    const int tid = threadIdx.x;
    const int b0  = blockIdx.x * 4;

    for (int i = tid; i < 512 * 4; i += 128) ((float*)h_s)[i] = 0.f;
    float c_reg[16];
#pragma unroll
    for (int j = 0; j < 16; ++j) c_reg[j] = 0.f;
    __syncthreads();

    for (int t = 0; t < 128; ++t) {
        float acc[16][4];
        // init accumulators from xp (bias already folded in)
#pragma unroll
        for (int i = 0; i < 16; ++i) {
            const float* xp; int rl, width;
            if (i < 8)       { xp = xpt; rl = tid + i * 128;        width = 1024; }
            else if (i < 12) { xp = xpa; rl = tid + (i - 8) * 128;  width = 512;  }
            else             { xp = xpv; rl = tid + (i - 12) * 128; width = 512;  }
#pragma unroll
            for (int b = 0; b < 4; ++b)
                acc[i][b] = xp[((size_t)(b0 + b) * 128 + t) * width + rl];
        }
        // k = 0..127: all modalities
        for (int k = 0; k < 128; ++k) {
            const float4 ha = *(const float4*)&h_s[k][0];
            const float4 hv = *(const float4*)&h_s[128 + k][0];
            const float4 ht = *(const float4*)&h_s[256 + k][0];
            const float* wr = WT + (size_t)k * 2048 + tid;
#pragma unroll
            for (int i = 0; i < 16; ++i) {
                float w = wr[i * 128];
                float4 h4 = (i < 8) ? ht : ((i < 12) ? ha : hv);
                acc[i][0] = fmaf(w, h4.x, acc[i][0]);
                acc[i][1] = fmaf(w, h4.y, acc[i][1]);
                acc[i][2] = fmaf(w, h4.z, acc[i][2]);
                acc[i][3] = fmaf(w, h4.w, acc[i][3]);
            }
        }
        // k = 128..255: text only
        for (int k = 128; k < 256; ++k) {
            const float4 ht = *(const float4*)&h_s[256 + k][0];
            const float* wr = WT + (size_t)k * 2048 + tid;
#pragma unroll
            for (int i = 0; i < 8; ++i) {
                float w = wr[i * 128];
                acc[i][0] = fmaf(w, ht.x, acc[i][0]);
                acc[i][1] = fmaf(w, ht.y, acc[i][1]);
                acc[i][2] = fmaf(w, ht.z, acc[i][2]);
                acc[i][3] = fmaf(w, ht.w, acc[i][3]);
            }
        }
        // stage gate pre-activations
#pragma unroll
        for (int i = 0; i < 16; ++i)
#pragma unroll
            for (int b = 0; b < 4; ++b)
                g_s[b][tid + i * 128] = acc[i][b];
        __syncthreads();

        // elementwise update: 16 (b,pos) pairs per thread
#pragma unroll
        for (int j = 0; j < 16; ++j) {
            int u = j * 128 + tid;
            int b = u >> 9, pos = u & 511;
            int gi, gf, gg, go;
            if (pos < 128)      { gi = 1024 + pos;              gf = gi + 128; gg = gi + 256; go = gi + 384; }
            else if (pos < 256) { gi = 1536 + (pos - 128);      gf = gi + 128; gg = gi + 256; go = gi + 384; }
            else                { gi = pos - 256;               gf = gi + 256; gg = gi + 512; go = gi + 768; }
            float vi = g_s[b][gi], vf = g_s[b][gf], vg = g_s[b][gg], vo = g_s[b][go];
            float c = sigm(vf) * c_reg[j] + sigm(vi) * tanh_(vg);
            c_reg[j] = c;
            float h = sigm(vo) * tanh_(c);
            h_s[pos][b] = h;
            z[((size_t)(b0 + b) * 128 + t) * 512 + pos] = h;
        }
        __syncthreads();
    }
}

// ---------------------------------------------------------------------------
// Fused f1/f2 head. Block = (b, 256-wide r tile). Computes
//   f1 = z[even] @ W1^T + b1          (K=512)
//   f2 = 1*W2[:,0] + z[even]@W2[:,1:513]^T + z[odd]@W2[:,513:1025]^T + b2
//   zf[b][r] = mean_k (f1 * f2)
// Pass A stages z[even] once and feeds BOTH W1 and W2a.
// ---------------------------------------------------------------------------
__global__ __launch_bounds__(256) void fuse_kernel(
    const float* __restrict__ z, const float* __restrict__ W1,
    const float* __restrict__ b1, const float* __restrict__ W2,
    const float* __restrict__ b2, float* __restrict__ zf)
{
    constexpr int BK = 16;
    __shared__ float Zs[BK][72];      // [kc][k]   (k = 0..63)
    __shared__ float W1s[BK][264];    // [kc][r]   (r tile = 256)
    __shared__ float W2s[BK][264];
    __shared__ float red[8][264];

    const int tid = threadIdx.x;
    const int b   = blockIdx.y;
    const int r0  = blockIdx.x * 256;
    const int tk  = (tid >> 5) * 8;   // k base
    const int tr  = (tid & 31) * 8;   // r base (within tile)

    float acc1[8][8], acc2[8][8];
#pragma unroll
    for (int i = 0; i < 8; ++i)
#pragma unroll
        for (int j = 0; j < 8; ++j) { acc1[i][j] = 0.f; acc2[i][j] = 0.f; }

    const int zk = tid >> 2;          // 0..63
    const int zc = (tid & 3) * 4;     // 0,4,8,12

    // ---- pass A: even timesteps, W1 + W2[:,1:513] ----
    for (int c0 = 0; c0 < 512; c0 += BK) {
        float4 v = *(const float4*)(z + ((size_t)b * 128 + 2 * zk) * 512 + c0 + zc);
        Zs[zc + 0][zk] = v.x; Zs[zc + 1][zk] = v.y; Zs[zc + 2][zk] = v.z; Zs[zc + 3][zk] = v.w;
        const float* w1p = W1 + (size_t)(r0 + tid) * 512 + c0;
        const float* w2p = W2 + (size_t)(r0 + tid) * 1025 + 1 + c0;
#pragma unroll
        for (int j = 0; j < 16; ++j) { W1s[j][tid] = w1p[j]; W2s[j][tid] = w2p[j]; }
        __syncthreads();
#pragma unroll
        for (int kc = 0; kc < BK; ++kc) {
            float a[8], w1[8], w2[8];
            *(float4*)&a[0]  = *(const float4*)&Zs[kc][tk];
            *(float4*)&a[4]  = *(const float4*)&Zs[kc][tk + 4];
            *(float4*)&w1[0] = *(const float4*)&W1s[kc][tr];
            *(float4*)&w1[4] = *(const float4*)&W1s[kc][tr + 4];
            *(float4*)&w2[0] = *(const float4*)&W2s[kc][tr];
            *(float4*)&w2[4] = *(const float4*)&W2s[kc][tr + 4];
#pragma unroll
            for (int i = 0; i < 8; ++i)
#pragma unroll
                for (int j = 0; j < 8; ++j) {
                    acc1[i][j] = fmaf(a[i], w1[j], acc1[i][j]);
                    acc2[i][j] = fmaf(a[i], w2[j], acc2[i][j]);
                }
        }
        __syncthreads();
    }
    // ---- pass B: odd timesteps, W2[:,513:1025] ----
    for (int c0 = 0; c0 < 512; c0 += BK) {
        float4 v = *(const float4*)(z + ((size_t)b * 128 + 2 * zk + 1) * 512 + c0 + zc);
        Zs[zc + 0][zk] = v.x; Zs[zc + 1][zk] = v.y; Zs[zc + 2][zk] = v.z; Zs[zc + 3][zk] = v.w;
        const float* w2p = W2 + (size_t)(r0 + tid) * 1025 + 513 + c0;
#pragma unroll
        for (int j = 0; j < 16; ++j) { W2s[j][tid] = w2p[j]; }
        __syncthreads();
#pragma unroll
        for (int kc = 0; kc < BK; ++kc) {
            float a[8], w2[8];
            *(float4*)&a[0]  = *(const float4*)&Zs[kc][tk];
            *(float4*)&a[4]  = *(const float4*)&Zs[kc][tk + 4];
            *(float4*)&w2[0] = *(const float4*)&W2s[kc][tr];
            *(float4*)&w2[4] = *(const float4*)&W2s[kc][tr + 4];
#pragma unroll
            for (int i = 0; i < 8; ++i)
#pragma unroll
                for (int j = 0; j < 8; ++j)
                    acc2[i][j] = fmaf(a[i], w2[j], acc2[i][j]);
        }
        __syncthreads();
    }

    // ---- epilogue: biases + ones column, product, reduce over k ----
#pragma unroll
    for (int j = 0; j < 8; ++j) {
        int r = r0 + tr + j;
        float bb1 = b1[r];
        float bb2 = b2[r] + W2[(size_t)r * 1025];   // ones column
        float s = 0.f;
#pragma unroll
        for (int i = 0; i < 8; ++i)
            s += (acc1[i][j] + bb1) * (acc2[i][j] + bb2);
        red[tid >> 5][tr + j] = s;
        __syncthreads();   // note: uniform loop -> all threads hit barrier
        if (j == 7) { }    // placeholder to keep structure simple
        __syncthreads();
    }
    // The two barriers above per iteration are overly conservative but
    // uniform; final reduce:
    {
        float s = 0.f;
#pragma unroll
        for (int g = 0; g < 8; ++g) s += red[g][tid];
        zf[(size_t)b * 2048 + r0 + tid] = s * (1.0f / 64.0f);
    }
}

// ---------------------------------------------------------------------------
// out[b][o] = sum_r fw[r] * zf[b][r*16+o]
// ---------------------------------------------------------------------------
__global__ void final_out(const float* __restrict__ zf, const float* __restrict__ fw,
                          float* __restrict__ out)
{
    int idx = blockIdx.x * 256 + threadIdx.x;   // 0..4095
    int b = idx >> 4, o = idx & 15;
    float s = 0.f;
#pragma unroll
    for (int r = 0; r < 128; ++r)
        s = fmaf(fw[r], zf[(size_t)b * 2048 + r * 16 + o], s);
    out[idx] = s;
}

extern "C" void kernel_launch(void* const* d_in, const int* in_sizes, int n_in,
                              void* d_out, int out_size, void* d_ws, size_t ws_size,
                              hipStream_t stream)
{
    const float* text_x  = (const float*)d_in[0];
    const float* audio_x = (const float*)d_in[1];
    const float* video_x = (const float*)d_in[2];
    const float* W_ih_t  = (const float*)d_in[3];
    const float* W_hh_t  = (const float*)d_in[4];
    const float* b_t     = (const float*)d_in[5];
    const float* W_ih_a  = (const float*)d_in[6];
    const float* W_hh_a  = (const float*)d_in[7];
    const float* b_a     = (const float*)d_in[8];
    const float* W_ih_v  = (const float*)d_in[9];
    const float* W_hh_v  = (const float*)d_in[10];
    const float* b_v     = (const float*)d_in[11];
    const float* W1      = (const float*)d_in[12];
    const float* b1      = (const float*)d_in[13];
    const float* W2      = (const float*)d_in[14];
    const float* b2      = (const float*)d_in[15];
    const float* fw      = (const float*)d_in[16];
    float* out = (float*)d_out;

    // workspace layout (floats); total ~340 MB
    float* ws   = (float*)d_ws;
    float* xpt  = ws;                       // 256*128*1024
    float* xpa  = xpt + (size_t)33554432;   // 256*128*512
    float* xpv  = xpa + (size_t)16777216;
    float* zbuf = xpv + (size_t)16777216;   // 256*128*512
    float* WT   = zbuf + (size_t)16777216;  // 256*2048
    float* zf   = WT + (size_t)524288;      // 256*2048

    gemm_bias<<<dim3(1024 / 128, 32768 / 128), 256, 0, stream>>>(text_x,  W_ih_t, b_t, xpt, 32768, 1024, 768);
    gemm_bias<<<dim3(512  / 128, 32768 / 128), 256, 0, stream>>>(audio_x, W_ih_a, b_a, xpa, 32768, 512, 74);
    gemm_bias<<<dim3(512  / 128, 32768 / 128), 256, 0, stream>>>(video_x, W_ih_v, b_v, xpv, 32768, 512, 35);
    wt_pack<<<2048, 256, 0, stream>>>(W_hh_t, W_hh_a, W_hh_v, WT);
    lstm_rec<<<64, 128, 0, stream>>>(xpt, xpa, xpv, WT, zbuf);
    fuse_kernel<<<dim3(8, 256), 256, 0, stream>>>(zbuf, W1, b1, W2, b2, zf);
    final_out<<<16, 256, 0, stream>>>(zf, fw, out);
}

// Round 2
// 4403.418 us; speedup vs baseline: 6.5530x; 6.5530x over previous
//
#include <hip/hip_runtime.h>
#include <hip/hip_bf16.h>
#include <math.h>

// B=256, T=128; text 768->256, audio 74->128, video 35->128
// z[b][t][512] = [audio(128) | video(128) | text(256)]

__device__ __forceinline__ float sigm(float x) { return 1.0f / (1.0f + __expf(-x)); }
__device__ __forceinline__ float tanh_(float x) {
    float ax = fabsf(x);
    float e  = __expf(-2.0f * ax);
    float t  = (1.0f - e) / (1.0f + e);
    return copysignf(t, x);
}

// ---------------------------------------------------------------------------
// Generic C[M,N] = A[M,K] * W[N,K]^T + bias[N].  M,N multiples of 128.
// ---------------------------------------------------------------------------
__global__ __launch_bounds__(256) void gemm_bias(
    const float* __restrict__ A, const float* __restrict__ W,
    const float* __restrict__ bias, float* __restrict__ C,
    int M, int N, int K)
{
    constexpr int BM = 128, BN = 128, BK = 16;
    __shared__ float As[BK][BM + 4];
    __shared__ float Ws[BK][BN + 4];

    const int tid = threadIdx.x;
    const int bm  = blockIdx.y * BM;
    const int bn  = blockIdx.x * BN;

    const int lr = tid >> 1;
    const int lc = (tid & 1) * 8;
    const int tm = (tid >> 4) * 8;
    const int tn = (tid & 15) * 8;

    float acc[8][8];
#pragma unroll
    for (int i = 0; i < 8; ++i)
#pragma unroll
        for (int j = 0; j < 8; ++j) acc[i][j] = 0.f;

    for (int k0 = 0; k0 < K; k0 += BK) {
#pragma unroll
        for (int j = 0; j < 8; ++j) {
            int kk = lc + j, kg = k0 + kk;
            float va = 0.f, vw = 0.f;
            if (kg < K) {
                va = A[(size_t)(bm + lr) * K + kg];
                vw = W[(size_t)(bn + lr) * K + kg];
            }
            As[kk][lr] = va;
            Ws[kk][lr] = vw;
        }
        __syncthreads();
#pragma unroll
        for (int kk = 0; kk < BK; ++kk) {
            float a[8], w[8];
            *(float4*)&a[0] = *(const float4*)&As[kk][tm];
            *(float4*)&a[4] = *(const float4*)&As[kk][tm + 4];
            *(float4*)&w[0] = *(const float4*)&Ws[kk][tn];
            *(float4*)&w[4] = *(const float4*)&Ws[kk][tn + 4];
#pragma unroll
            for (int i = 0; i < 8; ++i)
#pragma unroll
                for (int j = 0; j < 8; ++j)
                    acc[i][j] = fmaf(a[i], w[j], acc[i][j]);
        }
        __syncthreads();
    }

#pragma unroll
    for (int i = 0; i < 8; ++i)
#pragma unroll
        for (int j = 0; j < 8; ++j)
            C[(size_t)(bm + tm + i) * N + (bn + tn + j)] = acc[i][j] + bias[bn + tn + j];
}

// ---------------------------------------------------------------------------
// Pack W_hh transposed, k-minor-4:
//   WTt4[k4][col][kk] = W_hh_t[col][k4*4+kk]   (k4<64, col<1024)
//   WTa4[k4][col][kk] = W_hh_a[col][k4*4+kk]   (k4<32, col<512)
//   WTv4 likewise.
// ---------------------------------------------------------------------------
__global__ void w_pack4(const float* __restrict__ Wt, const float* __restrict__ Wa,
                        const float* __restrict__ Wv, float* __restrict__ WTt,
                        float* __restrict__ WTa, float* __restrict__ WTv)
{
    int idx = blockIdx.x * 256 + threadIdx.x;   // 393216 total
    if (idx < 262144) {
        int kk = idx & 3, col = (idx >> 2) & 1023, k4 = idx >> 12;
        WTt[idx] = Wt[(size_t)col * 256 + k4 * 4 + kk];
    } else if (idx < 327680) {
        int ia = idx - 262144;
        int kk = ia & 3, col = (ia >> 2) & 511, k4 = ia >> 11;
        WTa[ia] = Wa[(size_t)col * 128 + k4 * 4 + kk];
    } else if (idx < 393216) {
        int iv = idx - 327680;
        int kk = iv & 3, col = (iv >> 2) & 511, k4 = iv >> 11;
        WTv[iv] = Wv[(size_t)col * 128 + k4 * 4 + kk];
    }
}

// ---------------------------------------------------------------------------
// LSTM recurrence. 384 blocks x 256 threads:
//   bid <128  : text,  2 batches (b=2*bid,2*bid+1), thread=pos 0..255, 4 gates
//   bid <256  : audio, 2 batches, tid>>7 selects batch, pos=tid&127
//   else      : video, same structure as audio
// Thread owns all 4 gates of its pos -> c in register, no gate exchange.
// h broadcast via LDS; 2 barriers/step.
// ---------------------------------------------------------------------------
__global__ __launch_bounds__(256) void lstm_rec2(
    const float* __restrict__ xpt, const float* __restrict__ xpa,
    const float* __restrict__ xpv, const float* __restrict__ WTt,
    const float* __restrict__ WTa, const float* __restrict__ WTv,
    float* __restrict__ z)
{
    __shared__ float h_s[2][256];
    const int tid = threadIdx.x;
    const int bid = blockIdx.x;

    if (bid < 128) {
        const int b0 = bid * 2;
        float c0 = 0.f, c1 = 0.f;
        h_s[0][tid] = 0.f; h_s[1][tid] = 0.f;
        __syncthreads();
        for (int t = 0; t < 128; ++t) {
            const float* x0 = xpt + ((size_t)(b0 + 0) * 128 + t) * 1024;
            const float* x1 = xpt + ((size_t)(b0 + 1) * 128 + t) * 1024;
            float a00 = x0[tid], a01 = x0[256 + tid], a02 = x0[512 + tid], a03 = x0[768 + tid];
            float a10 = x1[tid], a11 = x1[256 + tid], a12 = x1[512 + tid], a13 = x1[768 + tid];
#pragma unroll 2
            for (int k4 = 0; k4 < 64; ++k4) {
                float4 h0 = *(const float4*)&h_s[0][k4 * 4];
                float4 h1 = *(const float4*)&h_s[1][k4 * 4];
                const float* w = WTt + (size_t)k4 * 4096 + tid * 4;
                float4 w0 = *(const float4*)&w[0];
                float4 w1 = *(const float4*)&w[1024];
                float4 w2 = *(const float4*)&w[2048];
                float4 w3 = *(const float4*)&w[3072];
                a00 = fmaf(w0.x, h0.x, a00); a00 = fmaf(w0.y, h0.y, a00);
                a00 = fmaf(w0.z, h0.z, a00); a00 = fmaf(w0.w, h0.w, a00);
                a01 = fmaf(w1.x, h0.x, a01); a01 = fmaf(w1.y, h0.y, a01);
                a01 = fmaf(w1.z, h0.z, a01); a01 = fmaf(w1.w, h0.w, a01);
                a02 = fmaf(w2.x, h0.x, a02); a02 = fmaf(w2.y, h0.y, a02);
                a02 = fmaf(w2.z, h0.z, a02); a02 = fmaf(w2.w, h0.w, a02);
                a03 = fmaf(w3.x, h0.x, a03); a03 = fmaf(w3.y, h0.y, a03);
                a03 = fmaf(w3.z, h0.z, a03); a03 = fmaf(w3.w, h0.w, a03);
                a10 = fmaf(w0.x, h1.x, a10); a10 = fmaf(w0.y, h1.y, a10);
                a10 = fmaf(w0.z, h1.z, a10); a10 = fmaf(w0.w, h1.w, a10);
                a11 = fmaf(w1.x, h1.x, a11); a11 = fmaf(w1.y, h1.y, a11);
                a11 = fmaf(w1.z, h1.z, a11); a11 = fmaf(w1.w, h1.w, a11);
                a12 = fmaf(w2.x, h1.x, a12); a12 = fmaf(w2.y, h1.y, a12);
                a12 = fmaf(w2.z, h1.z, a12); a12 = fmaf(w2.w, h1.w, a12);
                a13 = fmaf(w3.x, h1.x, a13); a13 = fmaf(w3.y, h1.y, a13);
                a13 = fmaf(w3.z, h1.z, a13); a13 = fmaf(w3.w, h1.w, a13);
            }
            __syncthreads();
            c0 = sigm(a01) * c0 + sigm(a00) * tanh_(a02);
            float hh0 = sigm(a03) * tanh_(c0);
            c1 = sigm(a11) * c1 + sigm(a10) * tanh_(a12);
            float hh1 = sigm(a13) * tanh_(c1);
            h_s[0][tid] = hh0;
            h_s[1][tid] = hh1;
            z[((size_t)(b0 + 0) * 128 + t) * 512 + 256 + tid] = hh0;
            z[((size_t)(b0 + 1) * 128 + t) * 512 + 256 + tid] = hh1;
            __syncthreads();
        }
    } else {
        const bool isA = bid < 256;
        const int b0 = (bid - (isA ? 128 : 256)) * 2;
        const int half = tid >> 7, pos = tid & 127;
        const int b = b0 + half;
        const float* xp = isA ? xpa : xpv;
        const float* W  = isA ? WTa : WTv;
        const int zoff  = isA ? 0 : 128;
        float c = 0.f;
        h_s[half][pos] = 0.f;
        __syncthreads();
        for (int t = 0; t < 128; ++t) {
            const float* x = xp + ((size_t)b * 128 + t) * 512;
            float a0 = x[pos], a1 = x[128 + pos], a2 = x[256 + pos], a3 = x[384 + pos];
#pragma unroll 2
            for (int k4 = 0; k4 < 32; ++k4) {
                float4 h4 = *(const float4*)&h_s[half][k4 * 4];
                const float* w = W + (size_t)k4 * 2048 + pos * 4;
                float4 w0 = *(const float4*)&w[0];
                float4 w1 = *(const float4*)&w[512];
                float4 w2 = *(const float4*)&w[1024];
                float4 w3 = *(const float4*)&w[1536];
                a0 = fmaf(w0.x, h4.x, a0); a0 = fmaf(w0.y, h4.y, a0);
                a0 = fmaf(w0.z, h4.z, a0); a0 = fmaf(w0.w, h4.w, a0);
                a1 = fmaf(w1.x, h4.x, a1); a1 = fmaf(w1.y, h4.y, a1);
                a1 = fmaf(w1.z, h4.z, a1); a1 = fmaf(w1.w, h4.w, a1);
                a2 = fmaf(w2.x, h4.x, a2); a2 = fmaf(w2.y, h4.y, a2);
                a2 = fmaf(w2.z, h4.z, a2); a2 = fmaf(w2.w, h4.w, a2);
                a3 = fmaf(w3.x, h4.x, a3); a3 = fmaf(w3.y, h4.y, a3);
                a3 = fmaf(w3.z, h4.z, a3); a3 = fmaf(w3.w, h4.w, a3);
            }
            __syncthreads();
            c = sigm(a1) * c + sigm(a0) * tanh_(a2);
            float hh = sigm(a3) * tanh_(c);
            h_s[half][pos] = hh;
            z[((size_t)b * 128 + t) * 512 + zoff + pos] = hh;
            __syncthreads();
        }
    }
}

// ---------------------------------------------------------------------------
// Fused f1/f2 head (unchanged from R0, correctness-verified).
// ---------------------------------------------------------------------------
__global__ __launch_bounds__(256) void fuse_kernel(
    const float* __restrict__ z, const float* __restrict__ W1,
    const float* __restrict__ b1, const float* __restrict__ W2,
    const float* __restrict__ b2, float* __restrict__ zf)
{
    constexpr int BK = 16;
    __shared__ float Zs[BK][72];
    __shared__ float W1s[BK][264];
    __shared__ float W2s[BK][264];
    __shared__ float red[8][264];

    const int tid = threadIdx.x;
    const int b   = blockIdx.y;
    const int r0  = blockIdx.x * 256;
    const int tk  = (tid >> 5) * 8;
    const int tr  = (tid & 31) * 8;

    float acc1[8][8], acc2[8][8];
#pragma unroll
    for (int i = 0; i < 8; ++i)
#pragma unroll
        for (int j = 0; j < 8; ++j) { acc1[i][j] = 0.f; acc2[i][j] = 0.f; }

    const int zk = tid >> 2;
    const int zc = (tid & 3) * 4;

    for (int c0 = 0; c0 < 512; c0 += BK) {
        float4 v = *(const float4*)(z + ((size_t)b * 128 + 2 * zk) * 512 + c0 + zc);
        Zs[zc + 0][zk] = v.x; Zs[zc + 1][zk] = v.y; Zs[zc + 2][zk] = v.z; Zs[zc + 3][zk] = v.w;
        const float* w1p = W1 + (size_t)(r0 + tid) * 512 + c0;
        const float* w2p = W2 + (size_t)(r0 + tid) * 1025 + 1 + c0;
#pragma unroll
        for (int j = 0; j < 16; ++j) { W1s[j][tid] = w1p[j]; W2s[j][tid] = w2p[j]; }
        __syncthreads();
#pragma unroll
        for (int kc = 0; kc < BK; ++kc) {
            float a[8], w1[8], w2[8];
            *(float4*)&a[0]  = *(const float4*)&Zs[kc][tk];
            *(float4*)&a[4]  = *(const float4*)&Zs[kc][tk + 4];
            *(float4*)&w1[0] = *(const float4*)&W1s[kc][tr];
            *(float4*)&w1[4] = *(const float4*)&W1s[kc][tr + 4];
            *(float4*)&w2[0] = *(const float4*)&W2s[kc][tr];
            *(float4*)&w2[4] = *(const float4*)&W2s[kc][tr + 4];
#pragma unroll
            for (int i = 0; i < 8; ++i)
#pragma unroll
                for (int j = 0; j < 8; ++j) {
                    acc1[i][j] = fmaf(a[i], w1[j], acc1[i][j]);
                    acc2[i][j] = fmaf(a[i], w2[j], acc2[i][j]);
                }
        }
        __syncthreads();
    }
    for (int c0 = 0; c0 < 512; c0 += BK) {
        float4 v = *(const float4*)(z + ((size_t)b * 128 + 2 * zk + 1) * 512 + c0 + zc);
        Zs[zc + 0][zk] = v.x; Zs[zc + 1][zk] = v.y; Zs[zc + 2][zk] = v.z; Zs[zc + 3][zk] = v.w;
        const float* w2p = W2 + (size_t)(r0 + tid) * 1025 + 513 + c0;
#pragma unroll
        for (int j = 0; j < 16; ++j) { W2s[j][tid] = w2p[j]; }
        __syncthreads();
#pragma unroll
        for (int kc = 0; kc < BK; ++kc) {
            float a[8], w2[8];
            *(float4*)&a[0]  = *(const float4*)&Zs[kc][tk];
            *(float4*)&a[4]  = *(const float4*)&Zs[kc][tk + 4];
            *(float4*)&w2[0] = *(const float4*)&W2s[kc][tr];
            *(float4*)&w2[4] = *(const float4*)&W2s[kc][tr + 4];
#pragma unroll
            for (int i = 0; i < 8; ++i)
#pragma unroll
                for (int j = 0; j < 8; ++j)
                    acc2[i][j] = fmaf(a[i], w2[j], acc2[i][j]);
        }
        __syncthreads();
    }

#pragma unroll
    for (int j = 0; j < 8; ++j) {
        int r = r0 + tr + j;
        float bb1 = b1[r];
        float bb2 = b2[r] + W2[(size_t)r * 1025];
        float s = 0.f;
#pragma unroll
        for (int i = 0; i < 8; ++i)
            s += (acc1[i][j] + bb1) * (acc2[i][j] + bb2);
        red[tid >> 5][tr + j] = s;
        __syncthreads();
        __syncthreads();
    }
    {
        float s = 0.f;
#pragma unroll
        for (int g = 0; g < 8; ++g) s += red[g][tid];
        zf[(size_t)b * 2048 + r0 + tid] = s * (1.0f / 64.0f);
    }
}

__global__ void final_out(const float* __restrict__ zf, const float* __restrict__ fw,
                          float* __restrict__ out)
{
    int idx = blockIdx.x * 256 + threadIdx.x;
    int b = idx >> 4, o = idx & 15;
    float s = 0.f;
#pragma unroll
    for (int r = 0; r < 128; ++r)
        s = fmaf(fw[r], zf[(size_t)b * 2048 + r * 16 + o], s);
    out[idx] = s;
}

extern "C" void kernel_launch(void* const* d_in, const int* in_sizes, int n_in,
                              void* d_out, int out_size, void* d_ws, size_t ws_size,
                              hipStream_t stream)
{
    const float* text_x  = (const float*)d_in[0];
    const float* audio_x = (const float*)d_in[1];
    const float* video_x = (const float*)d_in[2];
    const float* W_ih_t  = (const float*)d_in[3];
    const float* W_hh_t  = (const float*)d_in[4];
    const float* b_t     = (const float*)d_in[5];
    const float* W_ih_a  = (const float*)d_in[6];
    const float* W_hh_a  = (const float*)d_in[7];
    const float* b_a     = (const float*)d_in[8];
    const float* W_ih_v  = (const float*)d_in[9];
    const float* W_hh_v  = (const float*)d_in[10];
    const float* b_v     = (const float*)d_in[11];
    const float* W1      = (const float*)d_in[12];
    const float* b1      = (const float*)d_in[13];
    const float* W2      = (const float*)d_in[14];
    const float* b2      = (const float*)d_in[15];
    const float* fw      = (const float*)d_in[16];
    float* out = (float*)d_out;

    float* ws   = (float*)d_ws;
    float* xpt  = ws;                       // 256*128*1024
    float* xpa  = xpt + (size_t)33554432;   // 256*128*512
    float* xpv  = xpa + (size_t)16777216;
    float* zbuf = xpv + (size_t)16777216;   // 256*128*512
    float* WTt  = zbuf + (size_t)16777216;  // 64*1024*4
    float* WTa  = WTt + (size_t)262144;     // 32*512*4
    float* WTv  = WTa + (size_t)65536;
    float* zf   = WTv + (size_t)65536;      // 256*2048

    gemm_bias<<<dim3(1024 / 128, 32768 / 128), 256, 0, stream>>>(text_x,  W_ih_t, b_t, xpt, 32768, 1024, 768);
    gemm_bias<<<dim3(512  / 128, 32768 / 128), 256, 0, stream>>>(audio_x, W_ih_a, b_a, xpa, 32768, 512, 74);
    gemm_bias<<<dim3(512  / 128, 32768 / 128), 256, 0, stream>>>(video_x, W_ih_v, b_v, xpv, 32768, 512, 35);
    w_pack4<<<1536, 256, 0, stream>>>(W_hh_t, W_hh_a, W_hh_v, WTt, WTa, WTv);
    lstm_rec2<<<384, 256, 0, stream>>>(xpt, xpa, xpv, WTt, WTa, WTv, zbuf);
    fuse_kernel<<<dim3(8, 256), 256, 0, stream>>>(zbuf, W1, b1, W2, b2, zf);
    final_out<<<16, 256, 0, stream>>>(zf, fw, out);
}

// Round 3
// 2997.034 us; speedup vs baseline: 9.6280x; 1.4693x over previous
//
#include <hip/hip_runtime.h>
#include <hip/hip_bf16.h>
#include <math.h>

// B=256, T=128; text 768->256, audio 74->128, video 35->128
// z[b][t][512] = [audio(128) | video(128) | text(256)]  (stored bf16)

typedef __attribute__((ext_vector_type(8))) short short8;   // 8 bf16
typedef __attribute__((ext_vector_type(4))) float f32x4;

__device__ __forceinline__ float sigm(float x) { return 1.0f / (1.0f + __expf(-x)); }
__device__ __forceinline__ float tanh_(float x) {
    float ax = fabsf(x);
    float e  = __expf(-2.0f * ax);
    float t  = (1.0f - e) / (1.0f + e);
    return copysignf(t, x);
}
__device__ __forceinline__ ushort f2bf(float x) {
    __hip_bfloat16 h = __float2bfloat16(x);
    return *reinterpret_cast<ushort*>(&h);
}

// ---------------------------------------------------------------------------
// Generic C[M,N] = A[M,K] * W[N,K]^T + bias[N].  M,N multiples of 128.
// ---------------------------------------------------------------------------
__global__ __launch_bounds__(256) void gemm_bias(
    const float* __restrict__ A, const float* __restrict__ W,
    const float* __restrict__ bias, float* __restrict__ C,
    int M, int N, int K)
{
    constexpr int BM = 128, BN = 128, BK = 16;
    __shared__ float As[BK][BM + 4];
    __shared__ float Ws[BK][BN + 4];

    const int tid = threadIdx.x;
    const int bm  = blockIdx.y * BM;
    const int bn  = blockIdx.x * BN;

    const int lr = tid >> 1;
    const int lc = (tid & 1) * 8;
    const int tm = (tid >> 4) * 8;
    const int tn = (tid & 15) * 8;

    float acc[8][8];
#pragma unroll
    for (int i = 0; i < 8; ++i)
#pragma unroll
        for (int j = 0; j < 8; ++j) acc[i][j] = 0.f;

    for (int k0 = 0; k0 < K; k0 += BK) {
#pragma unroll
        for (int j = 0; j < 8; ++j) {
            int kk = lc + j, kg = k0 + kk;
            float va = 0.f, vw = 0.f;
            if (kg < K) {
                va = A[(size_t)(bm + lr) * K + kg];
                vw = W[(size_t)(bn + lr) * K + kg];
            }
            As[kk][lr] = va;
            Ws[kk][lr] = vw;
        }
        __syncthreads();
#pragma unroll
        for (int kk = 0; kk < BK; ++kk) {
            float a[8], w[8];
            *(float4*)&a[0] = *(const float4*)&As[kk][tm];
            *(float4*)&a[4] = *(const float4*)&As[kk][tm + 4];
            *(float4*)&w[0] = *(const float4*)&Ws[kk][tn];
            *(float4*)&w[4] = *(const float4*)&Ws[kk][tn + 4];
#pragma unroll
            for (int i = 0; i < 8; ++i)
#pragma unroll
                for (int j = 0; j < 8; ++j)
                    acc[i][j] = fmaf(a[i], w[j], acc[i][j]);
        }
        __syncthreads();
    }

#pragma unroll
    for (int i = 0; i < 8; ++i)
#pragma unroll
        for (int j = 0; j < 8; ++j)
            C[(size_t)(bm + tm + i) * N + (bn + tn + j)] = acc[i][j] + bias[bn + tn + j];
}

// ---------------------------------------------------------------------------
// Pack W_hh transposed, k-minor-4 (fp32, for the recurrence kernel).
// ---------------------------------------------------------------------------
__global__ void w_pack4(const float* __restrict__ Wt, const float* __restrict__ Wa,
                        const float* __restrict__ Wv, float* __restrict__ WTt,
                        float* __restrict__ WTa, float* __restrict__ WTv)
{
    int idx = blockIdx.x * 256 + threadIdx.x;
    if (idx < 262144) {
        int kk = idx & 3, col = (idx >> 2) & 1023, k4 = idx >> 12;
        WTt[idx] = Wt[(size_t)col * 256 + k4 * 4 + kk];
    } else if (idx < 327680) {
        int ia = idx - 262144;
        int kk = ia & 3, col = (ia >> 2) & 511, k4 = ia >> 11;
        WTa[ia] = Wa[(size_t)col * 128 + k4 * 4 + kk];
    } else if (idx < 393216) {
        int iv = idx - 327680;
        int kk = iv & 3, col = (iv >> 2) & 511, k4 = iv >> 11;
        WTv[iv] = Wv[(size_t)col * 128 + k4 * 4 + kk];
    }
}

// ---------------------------------------------------------------------------
// Pack W1 / W2 to bf16 for the MFMA fusion head.
//   W1b[r][c]  = bf16(W1[r][c])            c<512
//   W2ab[r][c] = bf16(W2[r][1+c])          (even-z half)
//   W2bb[r][c] = bf16(W2[r][513+c])        (odd-z half)
// ---------------------------------------------------------------------------
__global__ void wf_pack(const float* __restrict__ W1, const float* __restrict__ W2,
                        ushort* __restrict__ W1b, ushort* __restrict__ W2ab,
                        ushort* __restrict__ W2bb)
{
    int idx = blockIdx.x * 256 + threadIdx.x;   // 2048*512
    if (idx >= 1048576) return;
    int r = idx >> 9, c = idx & 511;
    W1b[idx]  = f2bf(W1[idx]);
    W2ab[idx] = f2bf(W2[(size_t)r * 1025 + 1 + c]);
    W2bb[idx] = f2bf(W2[(size_t)r * 1025 + 513 + c]);
}

// ---------------------------------------------------------------------------
// LSTM recurrence (fp32 math). Writes z as bf16.
// ---------------------------------------------------------------------------
__global__ __launch_bounds__(256) void lstm_rec2(
    const float* __restrict__ xpt, const float* __restrict__ xpa,
    const float* __restrict__ xpv, const float* __restrict__ WTt,
    const float* __restrict__ WTa, const float* __restrict__ WTv,
    ushort* __restrict__ zb)
{
    __shared__ float h_s[2][256];
    const int tid = threadIdx.x;
    const int bid = blockIdx.x;

    if (bid < 128) {
        const int b0 = bid * 2;
        float c0 = 0.f, c1 = 0.f;
        h_s[0][tid] = 0.f; h_s[1][tid] = 0.f;
        __syncthreads();
        for (int t = 0; t < 128; ++t) {
            const float* x0 = xpt + ((size_t)(b0 + 0) * 128 + t) * 1024;
            const float* x1 = xpt + ((size_t)(b0 + 1) * 128 + t) * 1024;
            float a00 = x0[tid], a01 = x0[256 + tid], a02 = x0[512 + tid], a03 = x0[768 + tid];
            float a10 = x1[tid], a11 = x1[256 + tid], a12 = x1[512 + tid], a13 = x1[768 + tid];
#pragma unroll 2
            for (int k4 = 0; k4 < 64; ++k4) {
                float4 h0 = *(const float4*)&h_s[0][k4 * 4];
                float4 h1 = *(const float4*)&h_s[1][k4 * 4];
                const float* w = WTt + (size_t)k4 * 4096 + tid * 4;
                float4 w0 = *(const float4*)&w[0];
                float4 w1 = *(const float4*)&w[1024];
                float4 w2 = *(const float4*)&w[2048];
                float4 w3 = *(const float4*)&w[3072];
                a00 = fmaf(w0.x, h0.x, a00); a00 = fmaf(w0.y, h0.y, a00);
                a00 = fmaf(w0.z, h0.z, a00); a00 = fmaf(w0.w, h0.w, a00);
                a01 = fmaf(w1.x, h0.x, a01); a01 = fmaf(w1.y, h0.y, a01);
                a01 = fmaf(w1.z, h0.z, a01); a01 = fmaf(w1.w, h0.w, a01);
                a02 = fmaf(w2.x, h0.x, a02); a02 = fmaf(w2.y, h0.y, a02);
                a02 = fmaf(w2.z, h0.z, a02); a02 = fmaf(w2.w, h0.w, a02);
                a03 = fmaf(w3.x, h0.x, a03); a03 = fmaf(w3.y, h0.y, a03);
                a03 = fmaf(w3.z, h0.z, a03); a03 = fmaf(w3.w, h0.w, a03);
                a10 = fmaf(w0.x, h1.x, a10); a10 = fmaf(w0.y, h1.y, a10);
                a10 = fmaf(w0.z, h1.z, a10); a10 = fmaf(w0.w, h1.w, a10);
                a11 = fmaf(w1.x, h1.x, a11); a11 = fmaf(w1.y, h1.y, a11);
                a11 = fmaf(w1.z, h1.z, a11); a11 = fmaf(w1.w, h1.w, a11);
                a12 = fmaf(w2.x, h1.x, a12); a12 = fmaf(w2.y, h1.y, a12);
                a12 = fmaf(w2.z, h1.z, a12); a12 = fmaf(w2.w, h1.w, a12);
                a13 = fmaf(w3.x, h1.x, a13); a13 = fmaf(w3.y, h1.y, a13);
                a13 = fmaf(w3.z, h1.z, a13); a13 = fmaf(w3.w, h1.w, a13);
            }
            __syncthreads();
            c0 = sigm(a01) * c0 + sigm(a00) * tanh_(a02);
            float hh0 = sigm(a03) * tanh_(c0);
            c1 = sigm(a11) * c1 + sigm(a10) * tanh_(a12);
            float hh1 = sigm(a13) * tanh_(c1);
            h_s[0][tid] = hh0;
            h_s[1][tid] = hh1;
            zb[((size_t)(b0 + 0) * 128 + t) * 512 + 256 + tid] = f2bf(hh0);
            zb[((size_t)(b0 + 1) * 128 + t) * 512 + 256 + tid] = f2bf(hh1);
            __syncthreads();
        }
    } else {
        const bool isA = bid < 256;
        const int b0 = (bid - (isA ? 128 : 256)) * 2;
        const int half = tid >> 7, pos = tid & 127;
        const int b = b0 + half;
        const float* xp = isA ? xpa : xpv;
        const float* W  = isA ? WTa : WTv;
        const int zoff  = isA ? 0 : 128;
        float c = 0.f;
        h_s[half][pos] = 0.f;
        __syncthreads();
        for (int t = 0; t < 128; ++t) {
            const float* x = xp + ((size_t)b * 128 + t) * 512;
            float a0 = x[pos], a1 = x[128 + pos], a2 = x[256 + pos], a3 = x[384 + pos];
#pragma unroll 2
            for (int k4 = 0; k4 < 32; ++k4) {
                float4 h4 = *(const float4*)&h_s[half][k4 * 4];
                const float* w = W + (size_t)k4 * 2048 + pos * 4;
                float4 w0 = *(const float4*)&w[0];
                float4 w1 = *(const float4*)&w[512];
                float4 w2 = *(const float4*)&w[1024];
                float4 w3 = *(const float4*)&w[1536];
                a0 = fmaf(w0.x, h4.x, a0); a0 = fmaf(w0.y, h4.y, a0);
                a0 = fmaf(w0.z, h4.z, a0); a0 = fmaf(w0.w, h4.w, a0);
                a1 = fmaf(w1.x, h4.x, a1); a1 = fmaf(w1.y, h4.y, a1);
                a1 = fmaf(w1.z, h4.z, a1); a1 = fmaf(w1.w, h4.w, a1);
                a2 = fmaf(w2.x, h4.x, a2); a2 = fmaf(w2.y, h4.y, a2);
                a2 = fmaf(w2.z, h4.z, a2); a2 = fmaf(w2.w, h4.w, a2);
                a3 = fmaf(w3.x, h4.x, a3); a3 = fmaf(w3.y, h4.y, a3);
                a3 = fmaf(w3.z, h4.z, a3); a3 = fmaf(w3.w, h4.w, a3);
            }
            __syncthreads();
            c = sigm(a1) * c + sigm(a0) * tanh_(a2);
            float hh = sigm(a3) * tanh_(c);
            h_s[half][pos] = hh;
            zb[((size_t)b * 128 + t) * 512 + zoff + pos] = f2bf(hh);
            __syncthreads();
        }
    }
}

// ---------------------------------------------------------------------------
// MFMA fusion head. Block = (r-tile 256, b). 4 waves, wave owns M=64 x N=64.
//   pass A (even t): acc1 += z_e*W1^T,  acc2 += z_e*W2a^T
//   pass B (odd  t): acc2 += z_o*W2b^T
// Epilogue: zf[b][r] = (1/64) sum_m (acc1+b1)(acc2+b2+W2[:,0])
// LDS rows padded to 40 bf16 (80B = 5x16B) -> bank-group walk, ~conflict-free.
// ---------------------------------------------------------------------------
__global__ __launch_bounds__(256) void fuse_mfma(
    const ushort* __restrict__ zb, const ushort* __restrict__ W1b,
    const ushort* __restrict__ W2ab, const ushort* __restrict__ W2bb,
    const float* __restrict__ b1, const float* __restrict__ b2,
    const float* __restrict__ W2, float* __restrict__ zf)
{
    constexpr int STR = 40;
    __shared__ ushort As[64 * STR];
    __shared__ ushort W1s[256 * STR];
    __shared__ ushort W2s[256 * STR];

    const int tid  = threadIdx.x;
    const int lane = tid & 63;
    const int wave = tid >> 6;
    const int b    = blockIdx.y;
    const int r0   = blockIdx.x * 256;
    const int n0w  = wave * 64;

    const int a_row  = tid >> 2;          // 0..63
    const int a_c8   = (tid & 3) * 8;     // 0,8,16,24
    const int fr_row = lane & 15;
    const int fr_k   = (lane >> 4) * 8;

    f32x4 acc1[4][4], acc2[4][4];
#pragma unroll
    for (int i = 0; i < 4; ++i)
#pragma unroll
        for (int j = 0; j < 4; ++j) {
            acc1[i][j] = (f32x4)(0.f);
            acc2[i][j] = (f32x4)(0.f);
        }

    for (int pass = 0; pass < 2; ++pass) {
        const ushort* wsrc = pass ? W2bb : W2ab;
        for (int c0 = 0; c0 < 512; c0 += 32) {
            // stage A tile: 64 timesteps x 32 channels
            {
                const int4 v = *(const int4*)(zb +
                    (((size_t)b * 128 + 2 * a_row + pass) * 512 + c0 + a_c8));
                *(int4*)&As[a_row * STR + a_c8] = v;
            }
            if (pass == 0) {
                const ushort* w1p = W1b + (size_t)(r0 + tid) * 512 + c0;
#pragma unroll
                for (int j = 0; j < 4; ++j)
                    *(int4*)&W1s[tid * STR + j * 8] = *(const int4*)(w1p + j * 8);
            }
            {
                const ushort* w2p = wsrc + (size_t)(r0 + tid) * 512 + c0;
#pragma unroll
                for (int j = 0; j < 4; ++j)
                    *(int4*)&W2s[tid * STR + j * 8] = *(const int4*)(w2p + j * 8);
            }
            __syncthreads();

            short8 af[4], w2f[4];
#pragma unroll
            for (int mi = 0; mi < 4; ++mi)
                af[mi] = *(const short8*)&As[(mi * 16 + fr_row) * STR + fr_k];
#pragma unroll
            for (int ni = 0; ni < 4; ++ni)
                w2f[ni] = *(const short8*)&W2s[(n0w + ni * 16 + fr_row) * STR + fr_k];

            if (pass == 0) {
                short8 w1f[4];
#pragma unroll
                for (int ni = 0; ni < 4; ++ni)
                    w1f[ni] = *(const short8*)&W1s[(n0w + ni * 16 + fr_row) * STR + fr_k];
#pragma unroll
                for (int mi = 0; mi < 4; ++mi)
#pragma unroll
                    for (int ni = 0; ni < 4; ++ni) {
                        acc1[mi][ni] = __builtin_amdgcn_mfma_f32_16x16x32_bf16(
                            af[mi], w1f[ni], acc1[mi][ni], 0, 0, 0);
                        acc2[mi][ni] = __builtin_amdgcn_mfma_f32_16x16x32_bf16(
                            af[mi], w2f[ni], acc2[mi][ni], 0, 0, 0);
                    }
            } else {
#pragma unroll
                for (int mi = 0; mi < 4; ++mi)
#pragma unroll
                    for (int ni = 0; ni < 4; ++ni)
                        acc2[mi][ni] = __builtin_amdgcn_mfma_f32_16x16x32_bf16(
                            af[mi], w2f[ni], acc2[mi][ni], 0, 0, 0);
            }
            __syncthreads();
        }
    }

    // epilogue: per-element (f1+b1)*(f2+b2'), mean over 64 rows, write zf
#pragma unroll
    for (int ni = 0; ni < 4; ++ni) {
        const int r = r0 + n0w + ni * 16 + fr_row;
        const float bb1 = b1[r];
        const float bb2 = b2[r] + W2[(size_t)r * 1025];   // ones column
        float s = 0.f;
#pragma unroll
        for (int mi = 0; mi < 4; ++mi)
#pragma unroll
            for (int q = 0; q < 4; ++q)
                s += (acc1[mi][ni][q] + bb1) * (acc2[mi][ni][q] + bb2);
        s += __shfl_xor(s, 16);
        s += __shfl_xor(s, 32);
        if ((lane >> 4) == 0)
            zf[(size_t)b * 2048 + r] = s * (1.0f / 64.0f);
    }
}

// ---------------------------------------------------------------------------
// out[b][o] = sum_r fw[r] * zf[b][r*16+o]
// ---------------------------------------------------------------------------
__global__ void final_out(const float* __restrict__ zf, const float* __restrict__ fw,
                          float* __restrict__ out)
{
    int idx = blockIdx.x * 256 + threadIdx.x;
    int b = idx >> 4, o = idx & 15;
    float s = 0.f;
#pragma unroll
    for (int r = 0; r < 128; ++r)
        s = fmaf(fw[r], zf[(size_t)b * 2048 + r * 16 + o], s);
    out[idx] = s;
}

extern "C" void kernel_launch(void* const* d_in, const int* in_sizes, int n_in,
                              void* d_out, int out_size, void* d_ws, size_t ws_size,
                              hipStream_t stream)
{
    const float* text_x  = (const float*)d_in[0];
    const float* audio_x = (const float*)d_in[1];
    const float* video_x = (const float*)d_in[2];
    const float* W_ih_t  = (const float*)d_in[3];
    const float* W_hh_t  = (const float*)d_in[4];
    const float* b_t     = (const float*)d_in[5];
    const float* W_ih_a  = (const float*)d_in[6];
    const float* W_hh_a  = (const float*)d_in[7];
    const float* b_a     = (const float*)d_in[8];
    const float* W_ih_v  = (const float*)d_in[9];
    const float* W_hh_v  = (const float*)d_in[10];
    const float* b_v     = (const float*)d_in[11];
    const float* W1      = (const float*)d_in[12];
    const float* b1      = (const float*)d_in[13];
    const float* W2      = (const float*)d_in[14];
    const float* b2      = (const float*)d_in[15];
    const float* fw      = (const float*)d_in[16];
    float* out = (float*)d_out;

    // workspace layout (bytes)
    char* base = (char*)d_ws;
    float*  xpt  = (float*)(base);                    // 32768*1024*4 = 134217728
    float*  xpa  = (float*)(base + 134217728);        // 32768*512*4  =  67108864
    float*  xpv  = (float*)(base + 201326592);        //                67108864
    float*  WTt  = (float*)(base + 268435456);        // 262144*4 = 1048576
    float*  WTa  = (float*)(base + 269484032);        //  65536*4 =  262144
    float*  WTv  = (float*)(base + 269746176);        //  65536*4 =  262144
    float*  zf   = (float*)(base + 270008320);        // 524288*4 = 2097152
    ushort* zbuf = (ushort*)(base + 272105472);       // 16777216*2 = 33554432
    ushort* W1b  = (ushort*)(base + 305659904);       // 1048576*2 = 2097152
    ushort* W2ab = (ushort*)(base + 307757056);       // 2097152
    ushort* W2bb = (ushort*)(base + 309854208);       // 2097152  (end ~297.5 MiB)

    gemm_bias<<<dim3(8, 256), 256, 0, stream>>>(text_x,  W_ih_t, b_t, xpt, 32768, 1024, 768);
    gemm_bias<<<dim3(4, 256), 256, 0, stream>>>(audio_x, W_ih_a, b_a, xpa, 32768, 512, 74);
    gemm_bias<<<dim3(4, 256), 256, 0, stream>>>(video_x, W_ih_v, b_v, xpv, 32768, 512, 35);
    w_pack4<<<1536, 256, 0, stream>>>(W_hh_t, W_hh_a, W_hh_v, WTt, WTa, WTv);
    wf_pack<<<4096, 256, 0, stream>>>(W1, W2, W1b, W2ab, W2bb);
    lstm_rec2<<<384, 256, 0, stream>>>(xpt, xpa, xpv, WTt, WTa, WTv, zbuf);
    fuse_mfma<<<dim3(8, 256), 256, 0, stream>>>(zbuf, W1b, W2ab, W2bb, b1, b2, W2, zf);
    final_out<<<16, 256, 0, stream>>>(zf, fw, out);
}

// Round 4
// 2911.863 us; speedup vs baseline: 9.9096x; 1.0292x over previous
//
#include <hip/hip_runtime.h>
#include <hip/hip_bf16.h>
#include <math.h>

// B=256, T=128; text 768->256, audio 74->128, video 35->128
// z[b][t][512] = [audio(128) | video(128) | text(256)]  (stored bf16)

typedef __attribute__((ext_vector_type(8))) short short8;   // 8 bf16
typedef __attribute__((ext_vector_type(4))) float f32x4;

__device__ __forceinline__ float sigm(float x) { return 1.0f / (1.0f + __expf(-x)); }
__device__ __forceinline__ float tanh_(float x) {
    float ax = fabsf(x);
    float e  = __expf(-2.0f * ax);
    float t  = (1.0f - e) / (1.0f + e);
    return copysignf(t, x);
}
__device__ __forceinline__ ushort f2bf(float x) {
    __hip_bfloat16 h = __float2bfloat16(x);
    return *reinterpret_cast<ushort*>(&h);
}
__device__ __forceinline__ float bflo(unsigned int u) { return __uint_as_float(u << 16); }
__device__ __forceinline__ float bfhi(unsigned int u) { return __uint_as_float(u & 0xffff0000u); }

// ---------------------------------------------------------------------------
// Generic C[M,N] = A[M,K] * W[N,K]^T + bias[N].  M,N multiples of 128.
// ---------------------------------------------------------------------------
__global__ __launch_bounds__(256) void gemm_bias(
    const float* __restrict__ A, const float* __restrict__ W,
    const float* __restrict__ bias, float* __restrict__ C,
    int M, int N, int K)
{
    constexpr int BM = 128, BN = 128, BK = 16;
    __shared__ float As[BK][BM + 4];
    __shared__ float Ws[BK][BN + 4];

    const int tid = threadIdx.x;
    const int bm  = blockIdx.y * BM;
    const int bn  = blockIdx.x * BN;

    const int lr = tid >> 1;
    const int lc = (tid & 1) * 8;
    const int tm = (tid >> 4) * 8;
    const int tn = (tid & 15) * 8;

    float acc[8][8];
#pragma unroll
    for (int i = 0; i < 8; ++i)
#pragma unroll
        for (int j = 0; j < 8; ++j) acc[i][j] = 0.f;

    for (int k0 = 0; k0 < K; k0 += BK) {
#pragma unroll
        for (int j = 0; j < 8; ++j) {
            int kk = lc + j, kg = k0 + kk;
            float va = 0.f, vw = 0.f;
            if (kg < K) {
                va = A[(size_t)(bm + lr) * K + kg];
                vw = W[(size_t)(bn + lr) * K + kg];
            }
            As[kk][lr] = va;
            Ws[kk][lr] = vw;
        }
        __syncthreads();
#pragma unroll
        for (int kk = 0; kk < BK; ++kk) {
            float a[8], w[8];
            *(float4*)&a[0] = *(const float4*)&As[kk][tm];
            *(float4*)&a[4] = *(const float4*)&As[kk][tm + 4];
            *(float4*)&w[0] = *(const float4*)&Ws[kk][tn];
            *(float4*)&w[4] = *(const float4*)&Ws[kk][tn + 4];
#pragma unroll
            for (int i = 0; i < 8; ++i)
#pragma unroll
                for (int j = 0; j < 8; ++j)
                    acc[i][j] = fmaf(a[i], w[j], acc[i][j]);
        }
        __syncthreads();
    }

#pragma unroll
    for (int i = 0; i < 8; ++i)
#pragma unroll
        for (int j = 0; j < 8; ++j)
            C[(size_t)(bm + tm + i) * N + (bn + tn + j)] = acc[i][j] + bias[bn + tn + j];
}

// ---------------------------------------------------------------------------
// Pack W_hh transposed, k-minor-4, bf16:
//   WTt[k4][col][kk] = bf16(W_hh_t[col][k4*4+kk])   (k4<64, col<1024)
//   WTa / WTv likewise (k4<32, col<512).
// ---------------------------------------------------------------------------
__global__ void w_pack4b(const float* __restrict__ Wt, const float* __restrict__ Wa,
                         const float* __restrict__ Wv, ushort* __restrict__ WTt,
                         ushort* __restrict__ WTa, ushort* __restrict__ WTv)
{
    int idx = blockIdx.x * 256 + threadIdx.x;
    if (idx < 262144) {
        int kk = idx & 3, col = (idx >> 2) & 1023, k4 = idx >> 12;
        WTt[idx] = f2bf(Wt[(size_t)col * 256 + k4 * 4 + kk]);
    } else if (idx < 327680) {
        int ia = idx - 262144;
        int kk = ia & 3, col = (ia >> 2) & 511, k4 = ia >> 11;
        WTa[ia] = f2bf(Wa[(size_t)col * 128 + k4 * 4 + kk]);
    } else if (idx < 393216) {
        int iv = idx - 327680;
        int kk = iv & 3, col = (iv >> 2) & 511, k4 = iv >> 11;
        WTv[iv] = f2bf(Wv[(size_t)col * 128 + k4 * 4 + kk]);
    }
}

// ---------------------------------------------------------------------------
// Pack W1 / W2 to bf16 for the MFMA fusion head.
// ---------------------------------------------------------------------------
__global__ void wf_pack(const float* __restrict__ W1, const float* __restrict__ W2,
                        ushort* __restrict__ W1b, ushort* __restrict__ W2ab,
                        ushort* __restrict__ W2bb)
{
    int idx = blockIdx.x * 256 + threadIdx.x;
    if (idx >= 1048576) return;
    int r = idx >> 9, c = idx & 511;
    W1b[idx]  = f2bf(W1[idx]);
    W2ab[idx] = f2bf(W2[(size_t)r * 1025 + 1 + c]);
    W2bb[idx] = f2bf(W2[(size_t)r * 1025 + 513 + c]);
}

// ---------------------------------------------------------------------------
// LSTM recurrence v3: 384 blocks x 512 threads (8 waves), k-split-2.
//   bid <128 : text,  2 batches. tid = kh(bit8) | pos(0..255).
//   bid <256 : audio, 2 batches. tid = bh(bit8) | kh(bit7) | pos(0..127).
//   else     : video, same as audio.
// kh=1 waves: xp init + their k-half partial -> p_s.
// kh=0 waves: their k-half partial + p_s + activations + h/z writes.
// W in bf16 (k-minor-4), unpacked in-register. fp32 state.
// ---------------------------------------------------------------------------
__global__ __launch_bounds__(512) void lstm_rec3(
    const float* __restrict__ xpt, const float* __restrict__ xpa,
    const float* __restrict__ xpv, const ushort* __restrict__ WTt,
    const ushort* __restrict__ WTa, const ushort* __restrict__ WTv,
    ushort* __restrict__ zb)
{
    __shared__ float h_s[2][256];
    __shared__ float p_s[8][256];

    const int tid = threadIdx.x;
    const int bid = blockIdx.x;

    if (bid < 128) {
        const int b0  = bid * 2;
        const int kh  = tid >> 8;        // wave-uniform
        const int pos = tid & 255;
        float c0 = 0.f, c1 = 0.f;
        if (kh == 0) { h_s[0][pos] = 0.f; h_s[1][pos] = 0.f; }
        __syncthreads();

        for (int t = 0; t < 128; ++t) {
            float a00, a01, a02, a03, a10, a11, a12, a13;
            if (kh == 1) {
                const float* x0 = xpt + ((size_t)(b0 + 0) * 128 + t) * 1024;
                const float* x1 = xpt + ((size_t)(b0 + 1) * 128 + t) * 1024;
                a00 = x0[pos]; a01 = x0[256 + pos]; a02 = x0[512 + pos]; a03 = x0[768 + pos];
                a10 = x1[pos]; a11 = x1[256 + pos]; a12 = x1[512 + pos]; a13 = x1[768 + pos];
            } else {
                a00 = a01 = a02 = a03 = a10 = a11 = a12 = a13 = 0.f;
            }
#pragma unroll 4
            for (int k4 = 0; k4 < 32; ++k4) {
                const int kidx = kh * 128 + k4 * 4;
                const float4 h0 = *(const float4*)&h_s[0][kidx];
                const float4 h1 = *(const float4*)&h_s[1][kidx];
                const ushort* w = WTt + (size_t)(kh * 32 + k4) * 4096 + pos * 4;
                const uint2 q0 = *(const uint2*)(w);
                const uint2 q1 = *(const uint2*)(w + 1024);
                const uint2 q2 = *(const uint2*)(w + 2048);
                const uint2 q3 = *(const uint2*)(w + 3072);
                float w0a = bflo(q0.x), w0b = bfhi(q0.x), w0c = bflo(q0.y), w0d = bfhi(q0.y);
                float w1a = bflo(q1.x), w1b = bfhi(q1.x), w1c = bflo(q1.y), w1d = bfhi(q1.y);
                float w2a = bflo(q2.x), w2b = bfhi(q2.x), w2c = bflo(q2.y), w2d = bfhi(q2.y);
                float w3a = bflo(q3.x), w3b = bfhi(q3.x), w3c = bflo(q3.y), w3d = bfhi(q3.y);
                a00 = fmaf(w0a, h0.x, a00); a00 = fmaf(w0b, h0.y, a00);
                a00 = fmaf(w0c, h0.z, a00); a00 = fmaf(w0d, h0.w, a00);
                a01 = fmaf(w1a, h0.x, a01); a01 = fmaf(w1b, h0.y, a01);
                a01 = fmaf(w1c, h0.z, a01); a01 = fmaf(w1d, h0.w, a01);
                a02 = fmaf(w2a, h0.x, a02); a02 = fmaf(w2b, h0.y, a02);
                a02 = fmaf(w2c, h0.z, a02); a02 = fmaf(w2d, h0.w, a02);
                a03 = fmaf(w3a, h0.x, a03); a03 = fmaf(w3b, h0.y, a03);
                a03 = fmaf(w3c, h0.z, a03); a03 = fmaf(w3d, h0.w, a03);
                a10 = fmaf(w0a, h1.x, a10); a10 = fmaf(w0b, h1.y, a10);
                a10 = fmaf(w0c, h1.z, a10); a10 = fmaf(w0d, h1.w, a10);
                a11 = fmaf(w1a, h1.x, a11); a11 = fmaf(w1b, h1.y, a11);
                a11 = fmaf(w1c, h1.z, a11); a11 = fmaf(w1d, h1.w, a11);
                a12 = fmaf(w2a, h1.x, a12); a12 = fmaf(w2b, h1.y, a12);
                a12 = fmaf(w2c, h1.z, a12); a12 = fmaf(w2d, h1.w, a12);
                a13 = fmaf(w3a, h1.x, a13); a13 = fmaf(w3b, h1.y, a13);
                a13 = fmaf(w3c, h1.z, a13); a13 = fmaf(w3d, h1.w, a13);
            }
            if (kh == 1) {
                p_s[0][pos] = a00; p_s[1][pos] = a01; p_s[2][pos] = a02; p_s[3][pos] = a03;
                p_s[4][pos] = a10; p_s[5][pos] = a11; p_s[6][pos] = a12; p_s[7][pos] = a13;
            }
            __syncthreads();
            if (kh == 0) {
                a00 += p_s[0][pos]; a01 += p_s[1][pos]; a02 += p_s[2][pos]; a03 += p_s[3][pos];
                a10 += p_s[4][pos]; a11 += p_s[5][pos]; a12 += p_s[6][pos]; a13 += p_s[7][pos];
                c0 = sigm(a01) * c0 + sigm(a00) * tanh_(a02);
                float hh0 = sigm(a03) * tanh_(c0);
                c1 = sigm(a11) * c1 + sigm(a10) * tanh_(a12);
                float hh1 = sigm(a13) * tanh_(c1);
                h_s[0][pos] = hh0;
                h_s[1][pos] = hh1;
                zb[((size_t)(b0 + 0) * 128 + t) * 512 + 256 + pos] = f2bf(hh0);
                zb[((size_t)(b0 + 1) * 128 + t) * 512 + 256 + pos] = f2bf(hh1);
            }
            __syncthreads();
        }
    } else {
        const bool isA = bid < 256;
        const int b0  = (bid - (isA ? 128 : 256)) * 2;
        const int bh  = tid >> 8;          // batch half, wave-uniform
        const int kh  = (tid >> 7) & 1;    // k half, wave-uniform
        const int pos = tid & 127;
        const int b   = b0 + bh;
        const float* xp = isA ? xpa : xpv;
        const ushort* W = isA ? WTa : WTv;
        const int zoff  = isA ? 0 : 128;
        float c = 0.f;
        if (kh == 0) h_s[bh][pos] = 0.f;
        __syncthreads();

        for (int t = 0; t < 128; ++t) {
            float a0, a1, a2, a3;
            if (kh == 1) {
                const float* x = xp + ((size_t)b * 128 + t) * 512;
                a0 = x[pos]; a1 = x[128 + pos]; a2 = x[256 + pos]; a3 = x[384 + pos];
            } else {
                a0 = a1 = a2 = a3 = 0.f;
            }
#pragma unroll 4
            for (int k4 = 0; k4 < 16; ++k4) {
                const int kidx = kh * 64 + k4 * 4;
                const float4 h4 = *(const float4*)&h_s[bh][kidx];
                const ushort* w = W + (size_t)(kh * 16 + k4) * 2048 + pos * 4;
                const uint2 q0 = *(const uint2*)(w);
                const uint2 q1 = *(const uint2*)(w + 512);
                const uint2 q2 = *(const uint2*)(w + 1024);
                const uint2 q3 = *(const uint2*)(w + 1536);
                float w0a = bflo(q0.x), w0b = bfhi(q0.x), w0c = bflo(q0.y), w0d = bfhi(q0.y);
                float w1a = bflo(q1.x), w1b = bfhi(q1.x), w1c = bflo(q1.y), w1d = bfhi(q1.y);
                float w2a = bflo(q2.x), w2b = bfhi(q2.x), w2c = bflo(q2.y), w2d = bfhi(q2.y);
                float w3a = bflo(q3.x), w3b = bfhi(q3.x), w3c = bflo(q3.y), w3d = bfhi(q3.y);
                a0 = fmaf(w0a, h4.x, a0); a0 = fmaf(w0b, h4.y, a0);
                a0 = fmaf(w0c, h4.z, a0); a0 = fmaf(w0d, h4.w, a0);
                a1 = fmaf(w1a, h4.x, a1); a1 = fmaf(w1b, h4.y, a1);
                a1 = fmaf(w1c, h4.z, a1); a1 = fmaf(w1d, h4.w, a1);
                a2 = fmaf(w2a, h4.x, a2); a2 = fmaf(w2b, h4.y, a2);
                a2 = fmaf(w2c, h4.z, a2); a2 = fmaf(w2d, h4.w, a2);
                a3 = fmaf(w3a, h4.x, a3); a3 = fmaf(w3b, h4.y, a3);
                a3 = fmaf(w3c, h4.z, a3); a3 = fmaf(w3d, h4.w, a3);
            }
            if (kh == 1) {
                p_s[bh * 4 + 0][pos] = a0; p_s[bh * 4 + 1][pos] = a1;
                p_s[bh * 4 + 2][pos] = a2; p_s[bh * 4 + 3][pos] = a3;
            }
            __syncthreads();
            if (kh == 0) {
                a0 += p_s[bh * 4 + 0][pos]; a1 += p_s[bh * 4 + 1][pos];
                a2 += p_s[bh * 4 + 2][pos]; a3 += p_s[bh * 4 + 3][pos];
                c = sigm(a1) * c + sigm(a0) * tanh_(a2);
                float hh = sigm(a3) * tanh_(c);
                h_s[bh][pos] = hh;
                zb[((size_t)b * 128 + t) * 512 + zoff + pos] = f2bf(hh);
            }
            __syncthreads();
        }
    }
}

// ---------------------------------------------------------------------------
// MFMA fusion head (unchanged from R2, verified).
// ---------------------------------------------------------------------------
__global__ __launch_bounds__(256) void fuse_mfma(
    const ushort* __restrict__ zb, const ushort* __restrict__ W1b,
    const ushort* __restrict__ W2ab, const ushort* __restrict__ W2bb,
    const float* __restrict__ b1, const float* __restrict__ b2,
    const float* __restrict__ W2, float* __restrict__ zf)
{
    constexpr int STR = 40;
    __shared__ ushort As[64 * STR];
    __shared__ ushort W1s[256 * STR];
    __shared__ ushort W2s[256 * STR];

    const int tid  = threadIdx.x;
    const int lane = tid & 63;
    const int wave = tid >> 6;
    const int b    = blockIdx.y;
    const int r0   = blockIdx.x * 256;
    const int n0w  = wave * 64;

    const int a_row  = tid >> 2;
    const int a_c8   = (tid & 3) * 8;
    const int fr_row = lane & 15;
    const int fr_k   = (lane >> 4) * 8;

    f32x4 acc1[4][4], acc2[4][4];
#pragma unroll
    for (int i = 0; i < 4; ++i)
#pragma unroll
        for (int j = 0; j < 4; ++j) {
            acc1[i][j] = (f32x4)(0.f);
            acc2[i][j] = (f32x4)(0.f);
        }

    for (int pass = 0; pass < 2; ++pass) {
        const ushort* wsrc = pass ? W2bb : W2ab;
        for (int c0 = 0; c0 < 512; c0 += 32) {
            {
                const int4 v = *(const int4*)(zb +
                    (((size_t)b * 128 + 2 * a_row + pass) * 512 + c0 + a_c8));
                *(int4*)&As[a_row * STR + a_c8] = v;
            }
            if (pass == 0) {
                const ushort* w1p = W1b + (size_t)(r0 + tid) * 512 + c0;
#pragma unroll
                for (int j = 0; j < 4; ++j)
                    *(int4*)&W1s[tid * STR + j * 8] = *(const int4*)(w1p + j * 8);
            }
            {
                const ushort* w2p = wsrc + (size_t)(r0 + tid) * 512 + c0;
#pragma unroll
                for (int j = 0; j < 4; ++j)
                    *(int4*)&W2s[tid * STR + j * 8] = *(const int4*)(w2p + j * 8);
            }
            __syncthreads();

            short8 af[4], w2f[4];
#pragma unroll
            for (int mi = 0; mi < 4; ++mi)
                af[mi] = *(const short8*)&As[(mi * 16 + fr_row) * STR + fr_k];
#pragma unroll
            for (int ni = 0; ni < 4; ++ni)
                w2f[ni] = *(const short8*)&W2s[(n0w + ni * 16 + fr_row) * STR + fr_k];

            if (pass == 0) {
                short8 w1f[4];
#pragma unroll
                for (int ni = 0; ni < 4; ++ni)
                    w1f[ni] = *(const short8*)&W1s[(n0w + ni * 16 + fr_row) * STR + fr_k];
#pragma unroll
                for (int mi = 0; mi < 4; ++mi)
#pragma unroll
                    for (int ni = 0; ni < 4; ++ni) {
                        acc1[mi][ni] = __builtin_amdgcn_mfma_f32_16x16x32_bf16(
                            af[mi], w1f[ni], acc1[mi][ni], 0, 0, 0);
                        acc2[mi][ni] = __builtin_amdgcn_mfma_f32_16x16x32_bf16(
                            af[mi], w2f[ni], acc2[mi][ni], 0, 0, 0);
                    }
            } else {
#pragma unroll
                for (int mi = 0; mi < 4; ++mi)
#pragma unroll
                    for (int ni = 0; ni < 4; ++ni)
                        acc2[mi][ni] = __builtin_amdgcn_mfma_f32_16x16x32_bf16(
                            af[mi], w2f[ni], acc2[mi][ni], 0, 0, 0);
            }
            __syncthreads();
        }
    }

#pragma unroll
    for (int ni = 0; ni < 4; ++ni) {
        const int r = r0 + n0w + ni * 16 + fr_row;
        const float bb1 = b1[r];
        const float bb2 = b2[r] + W2[(size_t)r * 1025];
        float s = 0.f;
#pragma unroll
        for (int mi = 0; mi < 4; ++mi)
#pragma unroll
            for (int q = 0; q < 4; ++q)
                s += (acc1[mi][ni][q] + bb1) * (acc2[mi][ni][q] + bb2);
        s += __shfl_xor(s, 16);
        s += __shfl_xor(s, 32);
        if ((lane >> 4) == 0)
            zf[(size_t)b * 2048 + r] = s * (1.0f / 64.0f);
    }
}

__global__ void final_out(const float* __restrict__ zf, const float* __restrict__ fw,
                          float* __restrict__ out)
{
    int idx = blockIdx.x * 256 + threadIdx.x;
    int b = idx >> 4, o = idx & 15;
    float s = 0.f;
#pragma unroll
    for (int r = 0; r < 128; ++r)
        s = fmaf(fw[r], zf[(size_t)b * 2048 + r * 16 + o], s);
    out[idx] = s;
}

extern "C" void kernel_launch(void* const* d_in, const int* in_sizes, int n_in,
                              void* d_out, int out_size, void* d_ws, size_t ws_size,
                              hipStream_t stream)
{
    const float* text_x  = (const float*)d_in[0];
    const float* audio_x = (const float*)d_in[1];
    const float* video_x = (const float*)d_in[2];
    const float* W_ih_t  = (const float*)d_in[3];
    const float* W_hh_t  = (const float*)d_in[4];
    const float* b_t     = (const float*)d_in[5];
    const float* W_ih_a  = (const float*)d_in[6];
    const float* W_hh_a  = (const float*)d_in[7];
    const float* b_a     = (const float*)d_in[8];
    const float* W_ih_v  = (const float*)d_in[9];
    const float* W_hh_v  = (const float*)d_in[10];
    const float* b_v     = (const float*)d_in[11];
    const float* W1      = (const float*)d_in[12];
    const float* b1      = (const float*)d_in[13];
    const float* W2      = (const float*)d_in[14];
    const float* b2      = (const float*)d_in[15];
    const float* fw      = (const float*)d_in[16];
    float* out = (float*)d_out;

    // workspace layout (bytes)
    char* base = (char*)d_ws;
    float*  xpt  = (float*)(base);                    // 134217728
    float*  xpa  = (float*)(base + 134217728);        //  67108864
    float*  xpv  = (float*)(base + 201326592);        //  67108864
    float*  zf   = (float*)(base + 268435456);        //   2097152
    ushort* zbuf = (ushort*)(base + 270532608);       //  33554432
    ushort* W1b  = (ushort*)(base + 304087040);       //   2097152
    ushort* W2ab = (ushort*)(base + 306184192);       //   2097152
    ushort* W2bb = (ushort*)(base + 308281344);       //   2097152
    ushort* WTtb = (ushort*)(base + 310378496);       //    524288
    ushort* WTab = (ushort*)(base + 310902784);       //    131072
    ushort* WTvb = (ushort*)(base + 311033856);       //    131072  (end ~296.7 MiB)

    gemm_bias<<<dim3(8, 256), 256, 0, stream>>>(text_x,  W_ih_t, b_t, xpt, 32768, 1024, 768);
    gemm_bias<<<dim3(4, 256), 256, 0, stream>>>(audio_x, W_ih_a, b_a, xpa, 32768, 512, 74);
    gemm_bias<<<dim3(4, 256), 256, 0, stream>>>(video_x, W_ih_v, b_v, xpv, 32768, 512, 35);
    w_pack4b<<<1536, 256, 0, stream>>>(W_hh_t, W_hh_a, W_hh_v, WTtb, WTab, WTvb);
    wf_pack<<<4096, 256, 0, stream>>>(W1, W2, W1b, W2ab, W2bb);
    lstm_rec3<<<384, 512, 0, stream>>>(xpt, xpa, xpv, WTtb, WTab, WTvb, zbuf);
    fuse_mfma<<<dim3(8, 256), 256, 0, stream>>>(zbuf, W1b, W2ab, W2bb, b1, b2, W2, zf);
    final_out<<<16, 256, 0, stream>>>(zf, fw, out);
}

// Round 5
// 2144.459 us; speedup vs baseline: 13.4558x; 1.3579x over previous
//
#include <hip/hip_runtime.h>
#include <hip/hip_bf16.h>
#include <math.h>

// B=256, T=128; text 768->256, audio 74->128, video 35->128
// z[b][t][512] = [audio(128) | video(128) | text(256)]  (bf16)
// xp buffers stored bf16, layout [b*128+t][4H] with gate cols [i|f|g|o].

typedef __attribute__((ext_vector_type(8))) short short8;   // 8 bf16
typedef __attribute__((ext_vector_type(4))) float f32x4;

__device__ __forceinline__ float sigm(float x) { return 1.0f / (1.0f + __expf(-x)); }
__device__ __forceinline__ float tanh_(float x) {
    float ax = fabsf(x);
    float e  = __expf(-2.0f * ax);
    float t  = (1.0f - e) / (1.0f + e);
    return copysignf(t, x);
}
__device__ __forceinline__ ushort f2bf(float x) {
    __hip_bfloat16 h = __float2bfloat16(x);
    return *reinterpret_cast<ushort*>(&h);
}
__device__ __forceinline__ float bf2f(ushort u) { return __uint_as_float(((unsigned)u) << 16); }

// ---------------------------------------------------------------------------
// MFMA GEMM: C_bf16[M,N] = bf16( A_f32[M,K] * W_f32[N,K]^T + bias[N] ).
// M,N multiples of 128. K arbitrary (zero-padded in staging). 256 thr, 4 waves,
// wave = 64x64 quadrant; BK=32; LDS stride 40 (bank-group walk, ~conflict-free).
// ---------------------------------------------------------------------------
__global__ __launch_bounds__(256) void gemm_mfma(
    const float* __restrict__ A, const float* __restrict__ W,
    const float* __restrict__ bias, ushort* __restrict__ C,
    int M, int N, int K)
{
    constexpr int STR = 40;
    __shared__ ushort As[128 * STR];
    __shared__ ushort Ws[128 * STR];

    const int tid  = threadIdx.x;
    const int lane = tid & 63;
    const int wave = tid >> 6;
    const int bm   = blockIdx.y * 128;
    const int bn   = blockIdx.x * 128;
    const int m0   = (wave >> 1) * 64;
    const int n0   = (wave & 1) * 64;
    const int row  = tid >> 1;
    const int kseg = (tid & 1) * 16;
    const int fr   = lane & 15;
    const int fk   = (lane >> 4) * 8;

    f32x4 acc[4][4];
#pragma unroll
    for (int i = 0; i < 4; ++i)
#pragma unroll
        for (int j = 0; j < 4; ++j) acc[i][j] = (f32x4)(0.f);

    const bool kmul4 = (K & 3) == 0;

    for (int k0 = 0; k0 < K; k0 += 32) {
        // stage A
        {
            const float* ap = A + (size_t)(bm + row) * K + k0 + kseg;
            if (kmul4 && (k0 + kseg + 16) <= K) {
                float4 v0 = *(const float4*)ap;
                float4 v1 = *(const float4*)(ap + 4);
                float4 v2 = *(const float4*)(ap + 8);
                float4 v3 = *(const float4*)(ap + 12);
                short8 o0, o1;
                o0[0]=f2bf(v0.x); o0[1]=f2bf(v0.y); o0[2]=f2bf(v0.z); o0[3]=f2bf(v0.w);
                o0[4]=f2bf(v1.x); o0[5]=f2bf(v1.y); o0[6]=f2bf(v1.z); o0[7]=f2bf(v1.w);
                o1[0]=f2bf(v2.x); o1[1]=f2bf(v2.y); o1[2]=f2bf(v2.z); o1[3]=f2bf(v2.w);
                o1[4]=f2bf(v3.x); o1[5]=f2bf(v3.y); o1[6]=f2bf(v3.z); o1[7]=f2bf(v3.w);
                *(short8*)&As[row * STR + kseg]     = o0;
                *(short8*)&As[row * STR + kseg + 8] = o1;
            } else {
#pragma unroll
                for (int j = 0; j < 16; ++j) {
                    int kk = k0 + kseg + j;
                    As[row * STR + kseg + j] = (kk < K) ? f2bf(ap[j]) : (ushort)0;
                }
            }
        }
        // stage W
        {
            const float* wp = W + (size_t)(bn + row) * K + k0 + kseg;
            if (kmul4 && (k0 + kseg + 16) <= K) {
                float4 v0 = *(const float4*)wp;
                float4 v1 = *(const float4*)(wp + 4);
                float4 v2 = *(const float4*)(wp + 8);
                float4 v3 = *(const float4*)(wp + 12);
                short8 o0, o1;
                o0[0]=f2bf(v0.x); o0[1]=f2bf(v0.y); o0[2]=f2bf(v0.z); o0[3]=f2bf(v0.w);
                o0[4]=f2bf(v1.x); o0[5]=f2bf(v1.y); o0[6]=f2bf(v1.z); o0[7]=f2bf(v1.w);
                o1[0]=f2bf(v2.x); o1[1]=f2bf(v2.y); o1[2]=f2bf(v2.z); o1[3]=f2bf(v2.w);
                o1[4]=f2bf(v3.x); o1[5]=f2bf(v3.y); o1[6]=f2bf(v3.z); o1[7]=f2bf(v3.w);
                *(short8*)&Ws[row * STR + kseg]     = o0;
                *(short8*)&Ws[row * STR + kseg + 8] = o1;
            } else {
#pragma unroll
                for (int j = 0; j < 16; ++j) {
                    int kk = k0 + kseg + j;
                    Ws[row * STR + kseg + j] = (kk < K) ? f2bf(wp[j]) : (ushort)0;
                }
            }
        }
        __syncthreads();

        short8 af[4], wf[4];
#pragma unroll
        for (int mi = 0; mi < 4; ++mi)
            af[mi] = *(const short8*)&As[(m0 + mi * 16 + fr) * STR + fk];
#pragma unroll
        for (int ni = 0; ni < 4; ++ni)
            wf[ni] = *(const short8*)&Ws[(n0 + ni * 16 + fr) * STR + fk];
#pragma unroll
        for (int mi = 0; mi < 4; ++mi)
#pragma unroll
            for (int ni = 0; ni < 4; ++ni)
                acc[mi][ni] = __builtin_amdgcn_mfma_f32_16x16x32_bf16(
                    af[mi], wf[ni], acc[mi][ni], 0, 0, 0);
        __syncthreads();
    }

#pragma unroll
    for (int ni = 0; ni < 4; ++ni) {
        float bb = bias[bn + n0 + ni * 16 + fr];
#pragma unroll
        for (int mi = 0; mi < 4; ++mi)
#pragma unroll
            for (int q = 0; q < 4; ++q)
                C[(size_t)(bm + m0 + mi * 16 + (lane >> 4) * 4 + q) * N +
                  bn + n0 + ni * 16 + fr] = f2bf(acc[mi][ni][q] + bb);
    }
}

// ---------------------------------------------------------------------------
// Pack W_hh into bf16 fragment-major layout:
//  text : WFt[((kt*8+w)*8 + g*2+s)*512 + n*32 + k8*8 + jj]
//         = bf16( W_hh_t[(g*256 + w*32 + s*16 + n)][kt*32 + k8*8 + jj] )
//  a/v  : WFx[((kt*8+w)*4 + g)*512 + n*32 + k8*8 + jj]
//         = bf16( W_hh_x[(g*128 + w*16 + n)][kt*32 + k8*8 + jj] )
// ---------------------------------------------------------------------------
__global__ void wfrag_pack(const float* __restrict__ Wt, const float* __restrict__ Wa,
                           const float* __restrict__ Wv, ushort* __restrict__ WFt,
                           ushort* __restrict__ WFa, ushort* __restrict__ WFv)
{
    int idx = blockIdx.x * 256 + threadIdx.x;   // 393216 total
    if (idx < 262144) {
        int e = idx;
        int jj = e & 7, k8 = (e >> 3) & 3, n = (e >> 5) & 15, s = (e >> 9) & 1;
        int g = (e >> 10) & 3, w = (e >> 12) & 7, kt = (e >> 15) & 7;
        WFt[e] = f2bf(Wt[(size_t)(g * 256 + w * 32 + s * 16 + n) * 256 + kt * 32 + k8 * 8 + jj]);
    } else if (idx < 327680) {
        int e = idx - 262144;
        int jj = e & 7, k8 = (e >> 3) & 3, n = (e >> 5) & 15;
        int g = (e >> 9) & 3, w = (e >> 11) & 7, kt = (e >> 14) & 3;
        WFa[e] = f2bf(Wa[(size_t)(g * 128 + w * 16 + n) * 128 + kt * 32 + k8 * 8 + jj]);
    } else if (idx < 393216) {
        int e = idx - 327680;
        int jj = e & 7, k8 = (e >> 3) & 3, n = (e >> 5) & 15;
        int g = (e >> 9) & 3, w = (e >> 11) & 7, kt = (e >> 14) & 3;
        WFv[e] = f2bf(Wv[(size_t)(g * 128 + w * 16 + n) * 128 + kt * 32 + k8 * 8 + jj]);
    }
}

// ---------------------------------------------------------------------------
// Pack W1 / W2 to bf16 for the MFMA fusion head.
// ---------------------------------------------------------------------------
__global__ void wf_pack(const float* __restrict__ W1, const float* __restrict__ W2,
                        ushort* __restrict__ W1b, ushort* __restrict__ W2ab,
                        ushort* __restrict__ W2bb)
{
    int idx = blockIdx.x * 256 + threadIdx.x;
    if (idx >= 1048576) return;
    int r = idx >> 9, c = idx & 511;
    W1b[idx]  = f2bf(W1[idx]);
    W2ab[idx] = f2bf(W2[(size_t)r * 1025 + 1 + c]);
    W2bb[idx] = f2bf(W2[(size_t)r * 1025 + 513 + c]);
}

// ---------------------------------------------------------------------------
// MFMA LSTM recurrence. 48 blocks x 512 thr (8 waves). Block = 16 batches of
// one modality. Wave owns a hidden-pos slice (all 4 gates) -> elementwise is
// in-register, c in VGPRs. Text: W kt0-4 VGPR-resident, kt5-6 in LDS
// (XOR-swizzled), kt7 re-read from L2-hot 64KB/step. a/v: W fully resident.
// h kept bf16 in LDS (XOR-swizzled); 2 barriers/step.
// acc is MFMA C-initialized with xp (bias already folded by gemm_mfma).
// ---------------------------------------------------------------------------
__global__ __launch_bounds__(512, 2) void lstm_mfma(
    const ushort* __restrict__ xpt, const ushort* __restrict__ xpa,
    const ushort* __restrict__ xpv, const ushort* __restrict__ WFt,
    const ushort* __restrict__ WFa, const ushort* __restrict__ WFv,
    ushort* __restrict__ zb)
{
    __shared__ ushort smem[69632];   // [0,65536): W-LDS (text); [65536,69632): h
    const int tid  = threadIdx.x;
    const int lane = tid & 63;
    const int w    = tid >> 6;       // wave 0..7
    const int np   = lane & 15;      // fragment row (batch for A, n-col for B)
    const int k8   = lane >> 4;      // 0..3
    const int mrow = k8 * 4;         // acc row base (batch)
    const int bid  = blockIdx.x;

    if (bid < 16) {
        // ---------------- text: H=256, K=256 (8 k-tiles) ----------------
        const int b0 = bid * 16;
        for (int c = tid; c < 8192; c += 512) {          // stage kt5,6 -> LDS
            int off = c * 16;
            int dst = (off & ~1023) | ((off & 1023) ^ (((off >> 6) & 7) << 4));
            *(int4*)((char*)&smem[0] + dst) = *(const int4*)((const char*)(WFt + 5 * 32768) + off);
        }
        short8 wres[5][8];
#pragma unroll
        for (int kt = 0; kt < 5; ++kt)
#pragma unroll
            for (int tt = 0; tt < 8; ++tt)
                wres[kt][tt] = *(const short8*)(WFt + (size_t)((kt * 8 + w) * 8 + tt) * 512 + np * 32 + k8 * 8);
        for (int i = tid; i < 4096; i += 512) smem[65536 + i] = 0;
        float c_st[2][4];
#pragma unroll
        for (int s = 0; s < 2; ++s)
#pragma unroll
            for (int q = 0; q < 4; ++q) c_st[s][q] = 0.f;
        __syncthreads();

        const size_t xrow0 = ((size_t)(b0 + mrow) * 128) * 1024 + w * 32 + np;
        for (int t = 0; t < 128; ++t) {
            const ushort* xr = xpt + xrow0 + (size_t)t * 1024;
            f32x4 acc[8];
#pragma unroll
            for (int g = 0; g < 4; ++g)
#pragma unroll
                for (int s = 0; s < 2; ++s) {
                    f32x4 a;
#pragma unroll
                    for (int q = 0; q < 4; ++q)
                        a[q] = bf2f(xr[(size_t)q * 131072 + g * 256 + s * 16]);
                    acc[g * 2 + s] = a;
                }
            short8 vw[8];                                  // kt7 stream (L2-hot)
#pragma unroll
            for (int tt = 0; tt < 8; ++tt)
                vw[tt] = *(const short8*)(WFt + (size_t)((7 * 8 + w) * 8 + tt) * 512 + np * 32 + k8 * 8);
            // resident kt0..4
#pragma unroll
            for (int kt = 0; kt < 5; ++kt) {
                int ab = np * 512 + kt * 64 + k8 * 16;
                short8 af = *(const short8*)((char*)&smem[65536] + (ab ^ ((np & 7) << 4)));
#pragma unroll
                for (int tt = 0; tt < 8; ++tt)
                    acc[tt] = __builtin_amdgcn_mfma_f32_16x16x32_bf16(af, wres[kt][tt], acc[tt], 0, 0, 0);
            }
            // LDS kt5,6
#pragma unroll
            for (int kk = 0; kk < 2; ++kk) {
                int ab = np * 512 + (5 + kk) * 64 + k8 * 16;
                short8 af = *(const short8*)((char*)&smem[65536] + (ab ^ ((np & 7) << 4)));
#pragma unroll
                for (int tt = 0; tt < 8; ++tt) {
                    int woff = ((kk * 8 + w) * 8 + tt) * 1024 + np * 64 + k8 * 16;
                    short8 wf = *(const short8*)((char*)&smem[0] +
                        ((woff & ~1023) | ((woff & 1023) ^ ((np & 7) << 4))));
                    acc[tt] = __builtin_amdgcn_mfma_f32_16x16x32_bf16(af, wf, acc[tt], 0, 0, 0);
                }
            }
            // stream kt7
            {
                int ab = np * 512 + 7 * 64 + k8 * 16;
                short8 af = *(const short8*)((char*)&smem[65536] + (ab ^ ((np & 7) << 4)));
#pragma unroll
                for (int tt = 0; tt < 8; ++tt)
                    acc[tt] = __builtin_amdgcn_mfma_f32_16x16x32_bf16(af, vw[tt], acc[tt], 0, 0, 0);
            }
            ushort hbf[2][4];
#pragma unroll
            for (int s = 0; s < 2; ++s)
#pragma unroll
                for (int q = 0; q < 4; ++q) {
                    float iv = acc[0 + s][q], fv = acc[2 + s][q];
                    float gv = acc[4 + s][q], ov = acc[6 + s][q];
                    float cc = sigm(fv) * c_st[s][q] + sigm(iv) * tanh_(gv);
                    c_st[s][q] = cc;
                    hbf[s][q] = f2bf(sigm(ov) * tanh_(cc));
                }
            __syncthreads();
#pragma unroll
            for (int s = 0; s < 2; ++s)
#pragma unroll
                for (int q = 0; q < 4; ++q) {
                    int m = mrow + q, p = w * 32 + s * 16 + np;
                    int byte = m * 512 + p * 2;
                    *(ushort*)((char*)&smem[65536] + (byte ^ ((m & 7) << 4))) = hbf[s][q];
                    zb[((size_t)(b0 + m) * 128 + t) * 512 + 256 + p] = hbf[s][q];
                }
            __syncthreads();
        }
    } else {
        // ---------------- audio / video: H=128, K=128 (4 k-tiles) ----------
        const bool isA = bid < 32;
        const int b0 = (bid - (isA ? 16 : 32)) * 16;
        const ushort* xp = isA ? xpa : xpv;
        const ushort* WF = isA ? WFa : WFv;
        const int zoff = isA ? 0 : 128;
        short8 wres[4][4];
#pragma unroll
        for (int kt = 0; kt < 4; ++kt)
#pragma unroll
            for (int g = 0; g < 4; ++g)
                wres[kt][g] = *(const short8*)(WF + (size_t)((kt * 8 + w) * 4 + g) * 512 + np * 32 + k8 * 8);
        for (int i = tid; i < 2048; i += 512) smem[i] = 0;
        float c_st[4];
#pragma unroll
        for (int q = 0; q < 4; ++q) c_st[q] = 0.f;
        __syncthreads();

        const size_t xrow0 = ((size_t)(b0 + mrow) * 128) * 512 + w * 16 + np;
        for (int t = 0; t < 128; ++t) {
            const ushort* xr = xp + xrow0 + (size_t)t * 512;
            f32x4 acc[4];
#pragma unroll
            for (int g = 0; g < 4; ++g) {
                f32x4 a;
#pragma unroll
                for (int q = 0; q < 4; ++q)
                    a[q] = bf2f(xr[(size_t)q * 65536 + g * 128]);
                acc[g] = a;
            }
#pragma unroll
            for (int kt = 0; kt < 4; ++kt) {
                int ab = np * 256 + kt * 64 + k8 * 16;
                short8 af = *(const short8*)((char*)&smem[0] + (ab ^ ((np & 7) << 4)));
#pragma unroll
                for (int g = 0; g < 4; ++g)
                    acc[g] = __builtin_amdgcn_mfma_f32_16x16x32_bf16(af, wres[kt][g], acc[g], 0, 0, 0);
            }
            ushort hbf[4];
#pragma unroll
            for (int q = 0; q < 4; ++q) {
                float iv = acc[0][q], fv = acc[1][q], gv = acc[2][q], ov = acc[3][q];
                float cc = sigm(fv) * c_st[q] + sigm(iv) * tanh_(gv);
                c_st[q] = cc;
                hbf[q] = f2bf(sigm(ov) * tanh_(cc));
            }
            __syncthreads();
#pragma unroll
            for (int q = 0; q < 4; ++q) {
                int m = mrow + q, p = w * 16 + np;
                int byte = m * 256 + p * 2;
                *(ushort*)((char*)&smem[0] + (byte ^ ((m & 7) << 4))) = hbf[q];
                zb[((size_t)(b0 + m) * 128 + t) * 512 + zoff + p] = hbf[q];
            }
            __syncthreads();
        }
    }
}

// ---------------------------------------------------------------------------
// MFMA fusion head (verified in R2/R3).
// ---------------------------------------------------------------------------
__global__ __launch_bounds__(256) void fuse_mfma(
    const ushort* __restrict__ zb, const ushort* __restrict__ W1b,
    const ushort* __restrict__ W2ab, const ushort* __restrict__ W2bb,
    const float* __restrict__ b1, const float* __restrict__ b2,
    const float* __restrict__ W2, float* __restrict__ zf)
{
    constexpr int STR = 40;
    __shared__ ushort As[64 * STR];
    __shared__ ushort W1s[256 * STR];
    __shared__ ushort W2s[256 * STR];

    const int tid  = threadIdx.x;
    const int lane = tid & 63;
    const int wave = tid >> 6;
    const int b    = blockIdx.y;
    const int r0   = blockIdx.x * 256;
    const int n0w  = wave * 64;

    const int a_row  = tid >> 2;
    const int a_c8   = (tid & 3) * 8;
    const int fr_row = lane & 15;
    const int fr_k   = (lane >> 4) * 8;

    f32x4 acc1[4][4], acc2[4][4];
#pragma unroll
    for (int i = 0; i < 4; ++i)
#pragma unroll
        for (int j = 0; j < 4; ++j) {
            acc1[i][j] = (f32x4)(0.f);
            acc2[i][j] = (f32x4)(0.f);
        }

    for (int pass = 0; pass < 2; ++pass) {
        const ushort* wsrc = pass ? W2bb : W2ab;
        for (int c0 = 0; c0 < 512; c0 += 32) {
            {
                const int4 v = *(const int4*)(zb +
                    (((size_t)b * 128 + 2 * a_row + pass) * 512 + c0 + a_c8));
                *(int4*)&As[a_row * STR + a_c8] = v;
            }
            if (pass == 0) {
                const ushort* w1p = W1b + (size_t)(r0 + tid) * 512 + c0;
#pragma unroll
                for (int j = 0; j < 4; ++j)
                    *(int4*)&W1s[tid * STR + j * 8] = *(const int4*)(w1p + j * 8);
            }
            {
                const ushort* w2p = wsrc + (size_t)(r0 + tid) * 512 + c0;
#pragma unroll
                for (int j = 0; j < 4; ++j)
                    *(int4*)&W2s[tid * STR + j * 8] = *(const int4*)(w2p + j * 8);
            }
            __syncthreads();

            short8 af[4], w2f[4];
#pragma unroll
            for (int mi = 0; mi < 4; ++mi)
                af[mi] = *(const short8*)&As[(mi * 16 + fr_row) * STR + fr_k];
#pragma unroll
            for (int ni = 0; ni < 4; ++ni)
                w2f[ni] = *(const short8*)&W2s[(n0w + ni * 16 + fr_row) * STR + fr_k];

            if (pass == 0) {
                short8 w1f[4];
#pragma unroll
                for (int ni = 0; ni < 4; ++ni)
                    w1f[ni] = *(const short8*)&W1s[(n0w + ni * 16 + fr_row) * STR + fr_k];
#pragma unroll
                for (int mi = 0; mi < 4; ++mi)
#pragma unroll
                    for (int ni = 0; ni < 4; ++ni) {
                        acc1[mi][ni] = __builtin_amdgcn_mfma_f32_16x16x32_bf16(
                            af[mi], w1f[ni], acc1[mi][ni], 0, 0, 0);
                        acc2[mi][ni] = __builtin_amdgcn_mfma_f32_16x16x32_bf16(
                            af[mi], w2f[ni], acc2[mi][ni], 0, 0, 0);
                    }
            } else {
#pragma unroll
                for (int mi = 0; mi < 4; ++mi)
#pragma unroll
                    for (int ni = 0; ni < 4; ++ni)
                        acc2[mi][ni] = __builtin_amdgcn_mfma_f32_16x16x32_bf16(
                            af[mi], w2f[ni], acc2[mi][ni], 0, 0, 0);
            }
            __syncthreads();
        }
    }

#pragma unroll
    for (int ni = 0; ni < 4; ++ni) {
        const int r = r0 + n0w + ni * 16 + fr_row;
        const float bb1 = b1[r];
        const float bb2 = b2[r] + W2[(size_t)r * 1025];
        float s = 0.f;
#pragma unroll
        for (int mi = 0; mi < 4; ++mi)
#pragma unroll
            for (int q = 0; q < 4; ++q)
                s += (acc1[mi][ni][q] + bb1) * (acc2[mi][ni][q] + bb2);
        s += __shfl_xor(s, 16);
        s += __shfl_xor(s, 32);
        if ((lane >> 4) == 0)
            zf[(size_t)b * 2048 + r] = s * (1.0f / 64.0f);
    }
}

__global__ void final_out(const float* __restrict__ zf, const float* __restrict__ fw,
                          float* __restrict__ out)
{
    int idx = blockIdx.x * 256 + threadIdx.x;
    int b = idx >> 4, o = idx & 15;
    float s = 0.f;
#pragma unroll
    for (int r = 0; r < 128; ++r)
        s = fmaf(fw[r], zf[(size_t)b * 2048 + r * 16 + o], s);
    out[idx] = s;
}

extern "C" void kernel_launch(void* const* d_in, const int* in_sizes, int n_in,
                              void* d_out, int out_size, void* d_ws, size_t ws_size,
                              hipStream_t stream)
{
    const float* text_x  = (const float*)d_in[0];
    const float* audio_x = (const float*)d_in[1];
    const float* video_x = (const float*)d_in[2];
    const float* W_ih_t  = (const float*)d_in[3];
    const float* W_hh_t  = (const float*)d_in[4];
    const float* b_t     = (const float*)d_in[5];
    const float* W_ih_a  = (const float*)d_in[6];
    const float* W_hh_a  = (const float*)d_in[7];
    const float* b_a     = (const float*)d_in[8];
    const float* W_ih_v  = (const float*)d_in[9];
    const float* W_hh_v  = (const float*)d_in[10];
    const float* b_v     = (const float*)d_in[11];
    const float* W1      = (const float*)d_in[12];
    const float* b1      = (const float*)d_in[13];
    const float* W2      = (const float*)d_in[14];
    const float* b2      = (const float*)d_in[15];
    const float* fw      = (const float*)d_in[16];
    float* out = (float*)d_out;

    // workspace layout (bytes)
    char* base = (char*)d_ws;
    ushort* xpt  = (ushort*)(base);                 // 32768*1024*2 = 67108864
    ushort* xpa  = (ushort*)(base + 67108864);      // 32768*512*2  = 33554432
    ushort* xpv  = (ushort*)(base + 100663296);     //               33554432
    ushort* zbuf = (ushort*)(base + 134217728);     //               33554432
    ushort* WFt  = (ushort*)(base + 167772160);     //   524288
    ushort* WFa  = (ushort*)(base + 168296448);     //   131072
    ushort* WFv  = (ushort*)(base + 168427520);     //   131072
    ushort* W1b  = (ushort*)(base + 168558592);     //  2097152
    ushort* W2ab = (ushort*)(base + 170655744);     //  2097152
    ushort* W2bb = (ushort*)(base + 172752896);     //  2097152
    float*  zf   = (float*)(base + 174850048);      //  2097152   (end ~168.8 MiB)

    gemm_mfma<<<dim3(8, 256), 256, 0, stream>>>(text_x,  W_ih_t, b_t, xpt, 32768, 1024, 768);
    gemm_mfma<<<dim3(4, 256), 256, 0, stream>>>(audio_x, W_ih_a, b_a, xpa, 32768, 512, 74);
    gemm_mfma<<<dim3(4, 256), 256, 0, stream>>>(video_x, W_ih_v, b_v, xpv, 32768, 512, 35);
    wfrag_pack<<<1536, 256, 0, stream>>>(W_hh_t, W_hh_a, W_hh_v, WFt, WFa, WFv);
    wf_pack<<<4096, 256, 0, stream>>>(W1, W2, W1b, W2ab, W2bb);
    lstm_mfma<<<48, 512, 0, stream>>>(xpt, xpa, xpv, WFt, WFa, WFv, zbuf);
    fuse_mfma<<<dim3(8, 256), 256, 0, stream>>>(zbuf, W1b, W2ab, W2bb, b1, b2, W2, zf);
    final_out<<<16, 256, 0, stream>>>(zf, fw, out);
}

// Round 6
// 2061.127 us; speedup vs baseline: 13.9999x; 1.0404x over previous
//
#include <hip/hip_runtime.h>
#include <hip/hip_bf16.h>
#include <math.h>

// B=256, T=128; text 768->256, audio 74->128, video 35->128
// z[b][t][512] = [audio(128) | video(128) | text(256)]  (bf16)
// xp buffers stored bf16 in LSTM-fragment layout (see gemm_mfma epilogue).

typedef __attribute__((ext_vector_type(8))) short short8;   // 8 bf16
typedef __attribute__((ext_vector_type(4))) float f32x4;

__device__ __forceinline__ float sigm(float x) { return 1.0f / (1.0f + __expf(-x)); }
__device__ __forceinline__ float tanh_(float x) {
    float ax = fabsf(x);
    float e  = __expf(-2.0f * ax);
    float t  = (1.0f - e) / (1.0f + e);
    return copysignf(t, x);
}
__device__ __forceinline__ ushort f2bf(float x) {
    __hip_bfloat16 h = __float2bfloat16(x);
    return *reinterpret_cast<ushort*>(&h);
}
__device__ __forceinline__ float bf2f(ushort u) { return __uint_as_float(((unsigned)u) << 16); }

// ---------------------------------------------------------------------------
// MFMA GEMM: gates = A_f32[M,K] * W_f32[N,K]^T + bias, written as bf16 into
// the LSTM fragment layout:
//  text (N=1024): idx = ((((b>>4)*128+t)*8 + w)*8 + (g*2+s))*256 + (b&15)*16 + pl
//                 col = g*256 + w*32 + s*16 + pl
//  a/v  (N=512):  idx = ((((b>>4)*128+t)*8 + w)*4 + g)*256 + (b&15)*16 + pl
//                 col = g*128 + w*16 + pl
// where row = b*128 + t.
// ---------------------------------------------------------------------------
__global__ __launch_bounds__(256) void gemm_mfma(
    const float* __restrict__ A, const float* __restrict__ W,
    const float* __restrict__ bias, ushort* __restrict__ C,
    int M, int N, int K)
{
    constexpr int STR = 40;
    __shared__ ushort As[128 * STR];
    __shared__ ushort Ws[128 * STR];

    const int tid  = threadIdx.x;
    const int lane = tid & 63;
    const int wave = tid >> 6;
    const int bm   = blockIdx.y * 128;
    const int bn   = blockIdx.x * 128;
    const int m0   = (wave >> 1) * 64;
    const int n0   = (wave & 1) * 64;
    const int row  = tid >> 1;
    const int kseg = (tid & 1) * 16;
    const int fr   = lane & 15;
    const int fk   = (lane >> 4) * 8;

    f32x4 acc[4][4];
#pragma unroll
    for (int i = 0; i < 4; ++i)
#pragma unroll
        for (int j = 0; j < 4; ++j) acc[i][j] = (f32x4)(0.f);

    const bool kmul4 = (K & 3) == 0;

    for (int k0 = 0; k0 < K; k0 += 32) {
        {
            const float* ap = A + (size_t)(bm + row) * K + k0 + kseg;
            if (kmul4 && (k0 + kseg + 16) <= K) {
                float4 v0 = *(const float4*)ap;
                float4 v1 = *(const float4*)(ap + 4);
                float4 v2 = *(const float4*)(ap + 8);
                float4 v3 = *(const float4*)(ap + 12);
                short8 o0, o1;
                o0[0]=f2bf(v0.x); o0[1]=f2bf(v0.y); o0[2]=f2bf(v0.z); o0[3]=f2bf(v0.w);
                o0[4]=f2bf(v1.x); o0[5]=f2bf(v1.y); o0[6]=f2bf(v1.z); o0[7]=f2bf(v1.w);
                o1[0]=f2bf(v2.x); o1[1]=f2bf(v2.y); o1[2]=f2bf(v2.z); o1[3]=f2bf(v2.w);
                o1[4]=f2bf(v3.x); o1[5]=f2bf(v3.y); o1[6]=f2bf(v3.z); o1[7]=f2bf(v3.w);
                *(short8*)&As[row * STR + kseg]     = o0;
                *(short8*)&As[row * STR + kseg + 8] = o1;
            } else {
#pragma unroll
                for (int j = 0; j < 16; ++j) {
                    int kk = k0 + kseg + j;
                    As[row * STR + kseg + j] = (kk < K) ? f2bf(ap[j]) : (ushort)0;
                }
            }
        }
        {
            const float* wp = W + (size_t)(bn + row) * K + k0 + kseg;
            if (kmul4 && (k0 + kseg + 16) <= K) {
                float4 v0 = *(const float4*)wp;
                float4 v1 = *(const float4*)(wp + 4);
                float4 v2 = *(const float4*)(wp + 8);
                float4 v3 = *(const float4*)(wp + 12);
                short8 o0, o1;
                o0[0]=f2bf(v0.x); o0[1]=f2bf(v0.y); o0[2]=f2bf(v0.z); o0[3]=f2bf(v0.w);
                o0[4]=f2bf(v1.x); o0[5]=f2bf(v1.y); o0[6]=f2bf(v1.z); o0[7]=f2bf(v1.w);
                o1[0]=f2bf(v2.x); o1[1]=f2bf(v2.y); o1[2]=f2bf(v2.z); o1[3]=f2bf(v2.w);
                o1[4]=f2bf(v3.x); o1[5]=f2bf(v3.y); o1[6]=f2bf(v3.z); o1[7]=f2bf(v3.w);
                *(short8*)&Ws[row * STR + kseg]     = o0;
                *(short8*)&Ws[row * STR + kseg + 8] = o1;
            } else {
#pragma unroll
                for (int j = 0; j < 16; ++j) {
                    int kk = k0 + kseg + j;
                    Ws[row * STR + kseg + j] = (kk < K) ? f2bf(wp[j]) : (ushort)0;
                }
            }
        }
        __syncthreads();

        short8 af[4], wf[4];
#pragma unroll
        for (int mi = 0; mi < 4; ++mi)
            af[mi] = *(const short8*)&As[(m0 + mi * 16 + fr) * STR + fk];
#pragma unroll
        for (int ni = 0; ni < 4; ++ni)
            wf[ni] = *(const short8*)&Ws[(n0 + ni * 16 + fr) * STR + fk];
#pragma unroll
        for (int mi = 0; mi < 4; ++mi)
#pragma unroll
            for (int ni = 0; ni < 4; ++ni)
                acc[mi][ni] = __builtin_amdgcn_mfma_f32_16x16x32_bf16(
                    af[mi], wf[ni], acc[mi][ni], 0, 0, 0);
        __syncthreads();
    }

    // epilogue: scatter into LSTM fragment layout
#pragma unroll
    for (int ni = 0; ni < 4; ++ni) {
        const int col = bn + n0 + ni * 16 + fr;
        const float bb = bias[col];
#pragma unroll
        for (int mi = 0; mi < 4; ++mi)
#pragma unroll
            for (int q = 0; q < 4; ++q) {
                int r  = bm + m0 + mi * 16 + (lane >> 4) * 4 + q;
                int b  = r >> 7, t = r & 127;
                size_t idx;
                if (N == 1024) {
                    int g = col >> 8, w = (col >> 5) & 7, s = (col >> 4) & 1, pl = col & 15;
                    idx = ((((size_t)(b >> 4) * 128 + t) * 8 + w) * 8 + (g * 2 + s)) * 256
                        + (size_t)(b & 15) * 16 + pl;
                } else {
                    int g = col >> 7, w = (col >> 4) & 7, pl = col & 15;
                    idx = ((((size_t)(b >> 4) * 128 + t) * 8 + w) * 4 + g) * 256
                        + (size_t)(b & 15) * 16 + pl;
                }
                C[idx] = f2bf(acc[mi][ni][q] + bb);
            }
    }
}

// ---------------------------------------------------------------------------
// Pack W_hh into bf16 fragment-major layout (A-operand for lstm MFMA):
//  text : WFt[((kt*8+w)*8 + g*2+s)*512 + n*32 + k8*8 + jj]
//         = bf16( W_hh_t[(g*256 + w*32 + s*16 + n)][kt*32 + k8*8 + jj] )
//  a/v  : WFx[((kt*8+w)*4 + g)*512 + n*32 + k8*8 + jj]
//         = bf16( W_hh_x[(g*128 + w*16 + n)][kt*32 + k8*8 + jj] )
// ---------------------------------------------------------------------------
__global__ void wfrag_pack(const float* __restrict__ Wt, const float* __restrict__ Wa,
                           const float* __restrict__ Wv, ushort* __restrict__ WFt,
                           ushort* __restrict__ WFa, ushort* __restrict__ WFv)
{
    int idx = blockIdx.x * 256 + threadIdx.x;
    if (idx < 262144) {
        int e = idx;
        int jj = e & 7, k8 = (e >> 3) & 3, n = (e >> 5) & 15, s = (e >> 9) & 1;
        int g = (e >> 10) & 3, w = (e >> 12) & 7, kt = (e >> 15) & 7;
        WFt[e] = f2bf(Wt[(size_t)(g * 256 + w * 32 + s * 16 + n) * 256 + kt * 32 + k8 * 8 + jj]);
    } else if (idx < 327680) {
        int e = idx - 262144;
        int jj = e & 7, k8 = (e >> 3) & 3, n = (e >> 5) & 15;
        int g = (e >> 9) & 3, w = (e >> 11) & 7, kt = (e >> 14) & 3;
        WFa[e] = f2bf(Wa[(size_t)(g * 128 + w * 16 + n) * 128 + kt * 32 + k8 * 8 + jj]);
    } else if (idx < 393216) {
        int e = idx - 327680;
        int jj = e & 7, k8 = (e >> 3) & 3, n = (e >> 5) & 15;
        int g = (e >> 9) & 3, w = (e >> 11) & 7, kt = (e >> 14) & 3;
        WFv[e] = f2bf(Wv[(size_t)(g * 128 + w * 16 + n) * 128 + kt * 32 + k8 * 8 + jj]);
    }
}

// ---------------------------------------------------------------------------
// Pack W1 / W2 to bf16 for the MFMA fusion head.
// ---------------------------------------------------------------------------
__global__ void wf_pack(const float* __restrict__ W1, const float* __restrict__ W2,
                        ushort* __restrict__ W1b, ushort* __restrict__ W2ab,
                        ushort* __restrict__ W2bb)
{
    int idx = blockIdx.x * 256 + threadIdx.x;
    if (idx >= 1048576) return;
    int r = idx >> 9, c = idx & 511;
    W1b[idx]  = f2bf(W1[idx]);
    W2ab[idx] = f2bf(W2[(size_t)r * 1025 + 1 + c]);
    W2bb[idx] = f2bf(W2[(size_t)r * 1025 + 513 + c]);
}

// ---------------------------------------------------------------------------
// MFMA LSTM recurrence v2. 48 blocks x 512 thr (8 waves); block = 16 batches
// of one modality. D = mfma(W_frag, h_frag) -> D[gatepos][batch]: each thread
// owns 4 consecutive hidden pos per (s) for ONE batch column -> b64 h-writes,
// contiguous xp loads, in-register c. W streamed from L2 2-deep (text) or
// VGPR-resident (a/v). LDS holds only h (8 KB, XOR-swizzled).
// xp is ADDED AFTER the MFMAs so its loads are off the critical path.
// ---------------------------------------------------------------------------
__global__ __launch_bounds__(512) void lstm_mfma2(
    const ushort* __restrict__ xpt, const ushort* __restrict__ xpa,
    const ushort* __restrict__ xpv, const ushort* __restrict__ WFt,
    const ushort* __restrict__ WFa, const ushort* __restrict__ WFv,
    ushort* __restrict__ zb)
{
    __shared__ ushort hbuf[4096];    // text [16][256]; a/v [16][128]
    const int tid  = threadIdx.x;
    const int lane = tid & 63;
    const int w    = tid >> 6;
    const int np   = lane & 15;      // batch column
    const int k8   = lane >> 4;      // k-chunk / row-quad
    const int bid  = blockIdx.x;

    if (bid < 16) {
        // ------------------------- text: H=256, K=256 -------------------------
        const int bt = bid;
        for (int i = tid; i < 2048; i += 512) ((uint*)hbuf)[i] = 0u;
        float c_st[2][4];
#pragma unroll
        for (int s = 0; s < 2; ++s)
#pragma unroll
            for (int q = 0; q < 4; ++q) c_st[s][q] = 0.f;
        __syncthreads();

        const ushort* xbase = xpt + (size_t)bt * 2097152 + w * 2048 + np * 16 + k8 * 4;
        const ushort* wbase = WFt + (size_t)(w * 8) * 512 + np * 32 + k8 * 8;
        const size_t  zrow  = ((size_t)(bt * 16 + np) * 128) * 512 + 256 + w * 32 + k8 * 4;

        for (int t = 0; t < 128; ++t) {
            // xp loads (consumed post-MFMA)
            uint2 xv[8];
            const ushort* xr = xbase + (size_t)t * 16384;
#pragma unroll
            for (int e = 0; e < 8; ++e)
                xv[e] = *(const uint2*)(xr + e * 256);
            // W stream: prime 2 k-tiles
            short8 wA[8], wB[8];
#pragma unroll
            for (int e = 0; e < 8; ++e) wA[e] = *(const short8*)(wbase + (size_t)e * 512);
#pragma unroll
            for (int e = 0; e < 8; ++e) wB[e] = *(const short8*)(wbase + (size_t)(64 + e) * 512);
            // h fragments (B-operand): batch=np, k-chunk k8, tile kt
            short8 hf[8];
#pragma unroll
            for (int kt = 0; kt < 8; ++kt) {
                int byte = np * 512 + kt * 64 + k8 * 16;
                hf[kt] = *(const short8*)((const char*)hbuf + (byte ^ ((np & 7) << 4)));
            }
            f32x4 acc[8];
#pragma unroll
            for (int e = 0; e < 8; ++e) acc[e] = (f32x4)(0.f);

#pragma unroll
            for (int kt = 0; kt < 8; ++kt) {
                if ((kt & 1) == 0) {
#pragma unroll
                    for (int e = 0; e < 8; ++e)
                        acc[e] = __builtin_amdgcn_mfma_f32_16x16x32_bf16(wA[e], hf[kt], acc[e], 0, 0, 0);
                    if (kt < 6) {
#pragma unroll
                        for (int e = 0; e < 8; ++e)
                            wA[e] = *(const short8*)(wbase + (size_t)((kt + 2) * 64 + e) * 512);
                    }
                } else {
#pragma unroll
                    for (int e = 0; e < 8; ++e)
                        acc[e] = __builtin_amdgcn_mfma_f32_16x16x32_bf16(wB[e], hf[kt], acc[e], 0, 0, 0);
                    if (kt < 6) {
#pragma unroll
                        for (int e = 0; e < 8; ++e)
                            wB[e] = *(const short8*)(wbase + (size_t)((kt + 2) * 64 + e) * 512);
                    }
                }
            }
            // add xp
#pragma unroll
            for (int e = 0; e < 8; ++e) {
                acc[e][0] += bf2f((ushort)(xv[e].x & 0xffffu));
                acc[e][1] += bf2f((ushort)(xv[e].x >> 16));
                acc[e][2] += bf2f((ushort)(xv[e].y & 0xffffu));
                acc[e][3] += bf2f((ushort)(xv[e].y >> 16));
            }
            // activations: e = g*2+s
            uint2 hw[2];
#pragma unroll
            for (int s = 0; s < 2; ++s) {
                ushort hq[4];
#pragma unroll
                for (int q = 0; q < 4; ++q) {
                    float iv = acc[0 + s][q], fv = acc[2 + s][q];
                    float gv = acc[4 + s][q], ov = acc[6 + s][q];
                    float cc = sigm(fv) * c_st[s][q] + sigm(iv) * tanh_(gv);
                    c_st[s][q] = cc;
                    hq[q] = f2bf(sigm(ov) * tanh_(cc));
                }
                hw[s].x = (uint)hq[0] | ((uint)hq[1] << 16);
                hw[s].y = (uint)hq[2] | ((uint)hq[3] << 16);
            }
            __syncthreads();
#pragma unroll
            for (int s = 0; s < 2; ++s) {
                int byte = np * 512 + w * 64 + s * 32 + k8 * 8;
                *(uint2*)((char*)hbuf + (byte ^ ((np & 7) << 4))) = hw[s];
                *(uint2*)(zb + zrow + (size_t)t * 512 + s * 16) = hw[s];
            }
            __syncthreads();
        }
    } else {
        // ----------------------- audio / video: H=128, K=128 -------------------
        const bool isA = bid < 32;
        const int bt = bid - (isA ? 16 : 32);
        const ushort* xp = isA ? xpa : xpv;
        const ushort* WF = isA ? WFa : WFv;
        const int zoff = isA ? 0 : 128;

        short8 wres[4][4];
#pragma unroll
        for (int kt = 0; kt < 4; ++kt)
#pragma unroll
            for (int g = 0; g < 4; ++g)
                wres[kt][g] = *(const short8*)(WF + (size_t)((kt * 8 + w) * 4 + g) * 512 + np * 32 + k8 * 8);
        for (int i = tid; i < 1024; i += 512) ((uint*)hbuf)[i] = 0u;
        float c_st[4];
#pragma unroll
        for (int q = 0; q < 4; ++q) c_st[q] = 0.f;
        __syncthreads();

        const ushort* xbase = xp + (size_t)bt * 1048576 + w * 1024 + np * 16 + k8 * 4;
        const size_t  zrow  = ((size_t)(bt * 16 + np) * 128) * 512 + zoff + w * 16 + k8 * 4;

        for (int t = 0; t < 128; ++t) {
            uint2 xv[4];
            const ushort* xr = xbase + (size_t)t * 8192;
#pragma unroll
            for (int g = 0; g < 4; ++g)
                xv[g] = *(const uint2*)(xr + g * 256);
            short8 hf[4];
#pragma unroll
            for (int kt = 0; kt < 4; ++kt) {
                int byte = np * 256 + kt * 64 + k8 * 16;
                hf[kt] = *(const short8*)((const char*)hbuf + (byte ^ ((np & 7) << 4)));
            }
            f32x4 acc[4];
#pragma unroll
            for (int g = 0; g < 4; ++g) acc[g] = (f32x4)(0.f);
#pragma unroll
            for (int kt = 0; kt < 4; ++kt)
#pragma unroll
                for (int g = 0; g < 4; ++g)
                    acc[g] = __builtin_amdgcn_mfma_f32_16x16x32_bf16(wres[kt][g], hf[kt], acc[g], 0, 0, 0);
#pragma unroll
            for (int g = 0; g < 4; ++g) {
                acc[g][0] += bf2f((ushort)(xv[g].x & 0xffffu));
                acc[g][1] += bf2f((ushort)(xv[g].x >> 16));
                acc[g][2] += bf2f((ushort)(xv[g].y & 0xffffu));
                acc[g][3] += bf2f((ushort)(xv[g].y >> 16));
            }
            ushort hq[4];
#pragma unroll
            for (int q = 0; q < 4; ++q) {
                float cc = sigm(acc[1][q]) * c_st[q] + sigm(acc[0][q]) * tanh_(acc[2][q]);
                c_st[q] = cc;
                hq[q] = f2bf(sigm(acc[3][q]) * tanh_(cc));
            }
            uint2 hw;
            hw.x = (uint)hq[0] | ((uint)hq[1] << 16);
            hw.y = (uint)hq[2] | ((uint)hq[3] << 16);
            __syncthreads();
            {
                int byte = np * 256 + w * 32 + k8 * 8;
                *(uint2*)((char*)hbuf + (byte ^ ((np & 7) << 4))) = hw;
                *(uint2*)(zb + zrow + (size_t)t * 512) = hw;
            }
            __syncthreads();
        }
    }
}

// ---------------------------------------------------------------------------
// MFMA fusion head (verified R2-R5).
// ---------------------------------------------------------------------------
__global__ __launch_bounds__(256) void fuse_mfma(
    const ushort* __restrict__ zb, const ushort* __restrict__ W1b,
    const ushort* __restrict__ W2ab, const ushort* __restrict__ W2bb,
    const float* __restrict__ b1, const float* __restrict__ b2,
    const float* __restrict__ W2, float* __restrict__ zf)
{
    constexpr int STR = 40;
    __shared__ ushort As[64 * STR];
    __shared__ ushort W1s[256 * STR];
    __shared__ ushort W2s[256 * STR];

    const int tid  = threadIdx.x;
    const int lane = tid & 63;
    const int wave = tid >> 6;
    const int b    = blockIdx.y;
    const int r0   = blockIdx.x * 256;
    const int n0w  = wave * 64;

    const int a_row  = tid >> 2;
    const int a_c8   = (tid & 3) * 8;
    const int fr_row = lane & 15;
    const int fr_k   = (lane >> 4) * 8;

    f32x4 acc1[4][4], acc2[4][4];
#pragma unroll
    for (int i = 0; i < 4; ++i)
#pragma unroll
        for (int j = 0; j < 4; ++j) {
            acc1[i][j] = (f32x4)(0.f);
            acc2[i][j] = (f32x4)(0.f);
        }

    for (int pass = 0; pass < 2; ++pass) {
        const ushort* wsrc = pass ? W2bb : W2ab;
        for (int c0 = 0; c0 < 512; c0 += 32) {
            {
                const int4 v = *(const int4*)(zb +
                    (((size_t)b * 128 + 2 * a_row + pass) * 512 + c0 + a_c8));
                *(int4*)&As[a_row * STR + a_c8] = v;
            }
            if (pass == 0) {
                const ushort* w1p = W1b + (size_t)(r0 + tid) * 512 + c0;
#pragma unroll
                for (int j = 0; j < 4; ++j)
                    *(int4*)&W1s[tid * STR + j * 8] = *(const int4*)(w1p + j * 8);
            }
            {
                const ushort* w2p = wsrc + (size_t)(r0 + tid) * 512 + c0;
#pragma unroll
                for (int j = 0; j < 4; ++j)
                    *(int4*)&W2s[tid * STR + j * 8] = *(const int4*)(w2p + j * 8);
            }
            __syncthreads();

            short8 af[4], w2f[4];
#pragma unroll
            for (int mi = 0; mi < 4; ++mi)
                af[mi] = *(const short8*)&As[(mi * 16 + fr_row) * STR + fr_k];
#pragma unroll
            for (int ni = 0; ni < 4; ++ni)
                w2f[ni] = *(const short8*)&W2s[(n0w + ni * 16 + fr_row) * STR + fr_k];

            if (pass == 0) {
                short8 w1f[4];
#pragma unroll
                for (int ni = 0; ni < 4; ++ni)
                    w1f[ni] = *(const short8*)&W1s[(n0w + ni * 16 + fr_row) * STR + fr_k];
#pragma unroll
                for (int mi = 0; mi < 4; ++mi)
#pragma unroll
                    for (int ni = 0; ni < 4; ++ni) {
                        acc1[mi][ni] = __builtin_amdgcn_mfma_f32_16x16x32_bf16(
                            af[mi], w1f[ni], acc1[mi][ni], 0, 0, 0);
                        acc2[mi][ni] = __builtin_amdgcn_mfma_f32_16x16x32_bf16(
                            af[mi], w2f[ni], acc2[mi][ni], 0, 0, 0);
                    }
            } else {
#pragma unroll
                for (int mi = 0; mi < 4; ++mi)
#pragma unroll
                    for (int ni = 0; ni < 4; ++ni)
                        acc2[mi][ni] = __builtin_amdgcn_mfma_f32_16x16x32_bf16(
                            af[mi], w2f[ni], acc2[mi][ni], 0, 0, 0);
            }
            __syncthreads();
        }
    }

#pragma unroll
    for (int ni = 0; ni < 4; ++ni) {
        const int r = r0 + n0w + ni * 16 + fr_row;
        const float bb1 = b1[r];
        const float bb2 = b2[r] + W2[(size_t)r * 1025];
        float s = 0.f;
#pragma unroll
        for (int mi = 0; mi < 4; ++mi)
#pragma unroll
            for (int q = 0; q < 4; ++q)
                s += (acc1[mi][ni][q] + bb1) * (acc2[mi][ni][q] + bb2);
        s += __shfl_xor(s, 16);
        s += __shfl_xor(s, 32);
        if ((lane >> 4) == 0)
            zf[(size_t)b * 2048 + r] = s * (1.0f / 64.0f);
    }
}

__global__ void final_out(const float* __restrict__ zf, const float* __restrict__ fw,
                          float* __restrict__ out)
{
    int idx = blockIdx.x * 256 + threadIdx.x;
    int b = idx >> 4, o = idx & 15;
    float s = 0.f;
#pragma unroll
    for (int r = 0; r < 128; ++r)
        s = fmaf(fw[r], zf[(size_t)b * 2048 + r * 16 + o], s);
    out[idx] = s;
}

extern "C" void kernel_launch(void* const* d_in, const int* in_sizes, int n_in,
                              void* d_out, int out_size, void* d_ws, size_t ws_size,
                              hipStream_t stream)
{
    const float* text_x  = (const float*)d_in[0];
    const float* audio_x = (const float*)d_in[1];
    const float* video_x = (const float*)d_in[2];
    const float* W_ih_t  = (const float*)d_in[3];
    const float* W_hh_t  = (const float*)d_in[4];
    const float* b_t     = (const float*)d_in[5];
    const float* W_ih_a  = (const float*)d_in[6];
    const float* W_hh_a  = (const float*)d_in[7];
    const float* b_a     = (const float*)d_in[8];
    const float* W_ih_v  = (const float*)d_in[9];
    const float* W_hh_v  = (const float*)d_in[10];
    const float* b_v     = (const float*)d_in[11];
    const float* W1      = (const float*)d_in[12];
    const float* b1      = (const float*)d_in[13];
    const float* W2      = (const float*)d_in[14];
    const float* b2      = (const float*)d_in[15];
    const float* fw      = (const float*)d_in[16];
    float* out = (float*)d_out;

    // workspace layout (bytes)
    char* base = (char*)d_ws;
    ushort* xpt  = (ushort*)(base);                 // 67108864
    ushort* xpa  = (ushort*)(base + 67108864);      // 33554432
    ushort* xpv  = (ushort*)(base + 100663296);     // 33554432
    ushort* zbuf = (ushort*)(base + 134217728);     // 33554432
    ushort* WFt  = (ushort*)(base + 167772160);     //   524288
    ushort* WFa  = (ushort*)(base + 168296448);     //   131072
    ushort* WFv  = (ushort*)(base + 168427520);     //   131072
    ushort* W1b  = (ushort*)(base + 168558592);     //  2097152
    ushort* W2ab = (ushort*)(base + 170655744);     //  2097152
    ushort* W2bb = (ushort*)(base + 172752896);     //  2097152
    float*  zf   = (float*)(base + 174850048);      //  2097152

    gemm_mfma<<<dim3(8, 256), 256, 0, stream>>>(text_x,  W_ih_t, b_t, xpt, 32768, 1024, 768);
    gemm_mfma<<<dim3(4, 256), 256, 0, stream>>>(audio_x, W_ih_a, b_a, xpa, 32768, 512, 74);
    gemm_mfma<<<dim3(4, 256), 256, 0, stream>>>(video_x, W_ih_v, b_v, xpv, 32768, 512, 35);
    wfrag_pack<<<1536, 256, 0, stream>>>(W_hh_t, W_hh_a, W_hh_v, WFt, WFa, WFv);
    wf_pack<<<4096, 256, 0, stream>>>(W1, W2, W1b, W2ab, W2bb);
    lstm_mfma2<<<48, 512, 0, stream>>>(xpt, xpa, xpv, WFt, WFa, WFv, zbuf);
    fuse_mfma<<<dim3(8, 256), 256, 0, stream>>>(zbuf, W1b, W2ab, W2bb, b1, b2, W2, zf);
    final_out<<<16, 256, 0, stream>>>(zf, fw, out);
}